// Round 14
// baseline (541.092 us; speedup 1.0000x reference)
//
#include <hip/hip_runtime.h>
#include <hip/hip_bf16.h>
#include <math.h>

#define CDIM 512
#define NTOK 3136
#define BATCH 8
#define MTOT (BATCH*NTOK)   // 25088
#define NHEAD 8
#define DHEAD 64
#define HW 56

typedef __attribute__((ext_vector_type(8))) short short8;
typedef __attribute__((ext_vector_type(4))) float f32x4;

__device__ __forceinline__ ushort f2bf(float f) {
    union { float f; unsigned int u; } v; v.f = f;
    unsigned int u = v.u + 0x7FFFu + ((v.u >> 16) & 1u);
    return (ushort)(u >> 16);
}
__device__ __forceinline__ float bf2f(ushort u) {
    union { unsigned int u; float f; } v; v.u = ((unsigned int)u) << 16;
    return v.f;
}

__device__ __forceinline__ void gload_lds16(const void* g, void* lds) {
    __builtin_amdgcn_global_load_lds((const __attribute__((address_space(1))) void*)g,
                                     (__attribute__((address_space(3))) void*)lds,
                                     16, 0, 0);
}

// ---------------- prep ----------------
__global__ void prep_kernel(const float* __restrict__ scale_p,
                            const float* __restrict__ power_p,
                            float* __restrict__ inv_scale,
                            float* __restrict__ power) {
    int c = threadIdx.x;
    if (c < CDIM) {
        float s = log1pf(expf(scale_p[c]));
        inv_scale[c] = 1.0f / s;
        power[c] = 1.0f + 4.0f / (1.0f + expf(-power_p[c]));
    }
}

__global__ __launch_bounds__(256) void cvt_bf16_kernel(const float* __restrict__ src,
                                                       ushort* __restrict__ dst, int n4) {
    int i = blockIdx.x * 256 + threadIdx.x;
    if (i < n4) {
        float4 f = ((const float4*)src)[i];
        ushort4 o;
        o.x = f2bf(f.x); o.y = f2bf(f.y); o.z = f2bf(f.z); o.w = f2bf(f.w);
        ((ushort4*)dst)[i] = o;
    }
}

// all three weight conversions in one launch
__global__ __launch_bounds__(256) void cvt_weights_kernel(const float* __restrict__ qg_w,
                                                          const float* __restrict__ kv_w,
                                                          const float* __restrict__ proj_w,
                                                          ushort* __restrict__ Wqg,
                                                          ushort* __restrict__ Wkv,
                                                          ushort* __restrict__ Wproj) {
    int i = blockIdx.x * 256 + threadIdx.x;
    const float* src; ushort* dst; int idx;
    if (i < 131072)      { src = qg_w;   dst = Wqg;   idx = i; }
    else if (i < 262144) { src = kv_w;   dst = Wkv;   idx = i - 131072; }
    else                 { src = proj_w; dst = Wproj; idx = i - 262144; }
    float4 f = ((const float4*)src)[idx];
    ushort4 o;
    o.x = f2bf(f.x); o.y = f2bf(f.y); o.z = f2bf(f.z); o.w = f2bf(f.w);
    ((ushort4*)dst)[idx] = o;
}

// ---------------- merged qg+kv GEMM: 128x128, 3-buffer counted-vmcnt pipeline (96KB LDS),
// XCD-swizzled, XOR epilogue, bf16 outputs.
// grid 3136. idp=(bid&7)*392+(bid>>3); mb=idp>>4, ob=idp&15.
// colg=ob*128: [0,512) Qbf | [512,1024) Gbf | [1024,1536) K->KF bf16 | [1536,2048) V bf16.
__global__ __launch_bounds__(256) void mgemm_qgkv(const ushort* __restrict__ A,
                                                  const ushort* __restrict__ Wqg,
                                                  const ushort* __restrict__ Wkv,
                                                  ushort* __restrict__ Qout,
                                                  ushort* __restrict__ Gout,
                                                  ushort* __restrict__ KFout,
                                                  ushort* __restrict__ Vout,
                                                  const float* __restrict__ pos,
                                                  const float* __restrict__ invs,
                                                  const float* __restrict__ powr) {
    __shared__ __align__(16) char smem[98304];
    ushort* At = (ushort*)smem;               // [3][128*64] = 48KB
    ushort* Bt = (ushort*)(smem + 49152);     // [3][128*64] = 48KB
    float*  Osh = (float*)smem;               // epilogue alias [128][128] (64KB)

    const int t = threadIdx.x;
    const int w = t >> 6, l = t & 63;
    const int wr = w >> 1, wc = w & 1;
    const int r8 = l >> 3, sl = l & 7;
    const int ss = sl ^ r8;

    const int bid = blockIdx.x;
    const int idp = (bid & 7) * 392 + (bid >> 3);
    const int mb = idp >> 4, ob = idp & 15;
    const int m0 = mb * 128;
    const ushort* Bp = (ob < 8) ? (Wqg + (size_t)ob * 128 * CDIM)
                                : (Wkv + (size_t)(ob - 8) * 128 * CDIM);

    auto stage = [&](int buf, int ks) {
        const int k0 = ks * 64;
        #pragma unroll
        for (int c = 0; c < 4; ++c) {
            int rc = (w * 4 + c) * 8 + r8;
            gload_lds16(A + (size_t)(m0 + rc) * CDIM + k0 + ss * 8, At + buf * 8192 + (w * 4 + c) * 512);
            gload_lds16(Bp + (size_t)rc * CDIM + k0 + ss * 8, Bt + buf * 8192 + (w * 4 + c) * 512);
        }
    };

    f32x4 acc[4][4] = {};
    stage(0, 0);
    stage(1, 1);
    for (int ks = 0; ks < 8; ++ks) {
        if (ks < 7) asm volatile("s_waitcnt vmcnt(8)" ::: "memory");
        else        asm volatile("s_waitcnt vmcnt(0)" ::: "memory");
        __builtin_amdgcn_s_barrier();
        if (ks + 2 < 8) stage((ks + 2) % 3, ks + 2);
        const int cur = ks % 3;
        #pragma unroll
        for (int kk = 0; kk < 2; ++kk) {
            short8 af[4], bfr[4];
            const int sbase = kk * 4 + (l >> 4);
            #pragma unroll
            for (int i = 0; i < 4; ++i) {
                int row = wr * 64 + i * 16 + (l & 15);
                af[i] = *(const short8*)&At[cur * 8192 + row * 64 + ((sbase ^ (row & 7)) * 8)];
                int rowb = wc * 64 + i * 16 + (l & 15);
                bfr[i] = *(const short8*)&Bt[cur * 8192 + rowb * 64 + ((sbase ^ (rowb & 7)) * 8)];
            }
            #pragma unroll
            for (int i = 0; i < 4; ++i)
                #pragma unroll
                for (int j = 0; j < 4; ++j)
                    acc[i][j] = __builtin_amdgcn_mfma_f32_16x16x32_bf16(af[i], bfr[j], acc[i][j], 0, 0, 0);
        }
    }
    __syncthreads();   // full drain before LDS reuse as Osh

    // acc -> Osh [128][128] with bit4-column-XOR
    #pragma unroll
    for (int i = 0; i < 4; ++i)
        #pragma unroll
        for (int j = 0; j < 4; ++j)
            #pragma unroll
            for (int rr = 0; rr < 4; ++rr) {
                int row = wr * 64 + i * 16 + (l >> 4) * 4 + rr;
                int col = wc * 64 + j * 16 + (l & 15);
                int pc = col ^ (((row >> 2) & 1) << 4);
                Osh[row * 128 + pc] = acc[i][j][rr];
            }
    __syncthreads();

    const int colbase = ob * 128;
    #pragma unroll
    for (int q = 0; q < 16; ++q) {
        int fi = q * 256 + t;
        int r = fi >> 5, c4 = (fi & 31) * 4;
        int pc4 = c4 ^ (((r >> 2) & 1) << 4);
        float4 v = *(float4*)&Osh[r * 128 + pc4];
        int m = m0 + r;
        if (colbase < 512) {
            ushort4 o;
            o.x = f2bf(v.x); o.y = f2bf(v.y); o.z = f2bf(v.z); o.w = f2bf(v.w);
            *(ushort4*)&Qout[(size_t)m * CDIM + colbase + c4] = o;
        } else if (colbase < 1024) {
            ushort4 o;
            o.x = f2bf(v.x); o.y = f2bf(v.y); o.z = f2bf(v.z); o.w = f2bf(v.w);
            *(ushort4*)&Gout[(size_t)m * CDIM + colbase - 512 + c4] = o;
        } else if (colbase < 1536) {
            int n = m % NTOK;
            int oc = colbase - 1024 + c4;
            float4 pv = *(const float4*)&pos[(size_t)n * CDIM + oc];
            float4 iv = *(const float4*)&invs[oc];
            float4 pw = *(const float4*)&powr[oc];
            float kx0 = (v.x + pv.x) * iv.x, kx1 = (v.y + pv.y) * iv.y;
            float kx2 = (v.z + pv.z) * iv.z, kx3 = (v.w + pv.w) * iv.w;
            float t0 = __powf(fabsf(kx0), pw.x), t1 = __powf(fabsf(kx1), pw.y);
            float t2 = __powf(fabsf(kx2), pw.z), t3 = __powf(fabsf(kx3), pw.w);
            ushort4 up, un;
            up.x = kx0 > 0.f ? f2bf(t0) : 0; un.x = kx0 < 0.f ? f2bf(t0) : 0;
            up.y = kx1 > 0.f ? f2bf(t1) : 0; un.y = kx1 < 0.f ? f2bf(t1) : 0;
            up.z = kx2 > 0.f ? f2bf(t2) : 0; un.z = kx2 < 0.f ? f2bf(t2) : 0;
            up.w = kx3 > 0.f ? f2bf(t3) : 0; un.w = kx3 < 0.f ? f2bf(t3) : 0;
            ushort* dst = KFout + (size_t)m * 1024 + ((oc >> 6) << 7) + (oc & 63);
            *(ushort4*)dst = up;
            *(ushort4*)(dst + 64) = un;
        } else {
            ushort4 o;
            o.x = f2bf(v.x); o.y = f2bf(v.y); o.z = f2bf(v.z); o.w = f2bf(v.w);
            *(ushort4*)&Vout[(size_t)m * CDIM + colbase - 1536 + c4] = o;
        }
    }
}

// ---------------- proj GEMM: 3-buffer counted-vmcnt pipeline, XOR fp32 epilogue --------
__global__ __launch_bounds__(256) void mgemm_proj(const ushort* __restrict__ A,
                                                  const ushort* __restrict__ W,
                                                  float* __restrict__ out,
                                                  const float* __restrict__ pb) {
    __shared__ __align__(16) char smem[98304];
    ushort* At = (ushort*)smem;
    ushort* Bt = (ushort*)(smem + 49152);
    float*  Osh = (float*)smem;

    const int t = threadIdx.x;
    const int w = t >> 6, l = t & 63;
    const int wr = w >> 1, wc = w & 1;
    const int r8 = l >> 3, sl = l & 7;
    const int ss = sl ^ r8;

    const int bid = blockIdx.x;
    const int idp = (bid & 7) * 98 + (bid >> 3);
    const int mb = idp >> 2, ob = idp & 3;
    const int m0 = mb * 128;
    const ushort* Bp = W + (size_t)ob * 128 * CDIM;

    auto stage = [&](int buf, int ks) {
        const int k0 = ks * 64;
        #pragma unroll
        for (int c = 0; c < 4; ++c) {
            int rc = (w * 4 + c) * 8 + r8;
            gload_lds16(A + (size_t)(m0 + rc) * CDIM + k0 + ss * 8, At + buf * 8192 + (w * 4 + c) * 512);
            gload_lds16(Bp + (size_t)rc * CDIM + k0 + ss * 8, Bt + buf * 8192 + (w * 4 + c) * 512);
        }
    };

    f32x4 acc[4][4] = {};
    stage(0, 0);
    stage(1, 1);
    for (int ks = 0; ks < 8; ++ks) {
        if (ks < 7) asm volatile("s_waitcnt vmcnt(8)" ::: "memory");
        else        asm volatile("s_waitcnt vmcnt(0)" ::: "memory");
        __builtin_amdgcn_s_barrier();
        if (ks + 2 < 8) stage((ks + 2) % 3, ks + 2);
        const int cur = ks % 3;
        #pragma unroll
        for (int kk = 0; kk < 2; ++kk) {
            short8 af[4], bfr[4];
            const int sbase = kk * 4 + (l >> 4);
            #pragma unroll
            for (int i = 0; i < 4; ++i) {
                int row = wr * 64 + i * 16 + (l & 15);
                af[i] = *(const short8*)&At[cur * 8192 + row * 64 + ((sbase ^ (row & 7)) * 8)];
                int rowb = wc * 64 + i * 16 + (l & 15);
                bfr[i] = *(const short8*)&Bt[cur * 8192 + rowb * 64 + ((sbase ^ (rowb & 7)) * 8)];
            }
            #pragma unroll
            for (int i = 0; i < 4; ++i)
                #pragma unroll
                for (int j = 0; j < 4; ++j)
                    acc[i][j] = __builtin_amdgcn_mfma_f32_16x16x32_bf16(af[i], bfr[j], acc[i][j], 0, 0, 0);
        }
    }
    __syncthreads();

    #pragma unroll
    for (int i = 0; i < 4; ++i)
        #pragma unroll
        for (int j = 0; j < 4; ++j)
            #pragma unroll
            for (int rr = 0; rr < 4; ++rr) {
                int row = wr * 64 + i * 16 + (l >> 4) * 4 + rr;
                int col = wc * 64 + j * 16 + (l & 15);
                int pc = col ^ (((row >> 2) & 1) << 4);
                Osh[row * 128 + pc] = acc[i][j][rr];
            }
    __syncthreads();

    const int colbase = ob * 128;
    #pragma unroll
    for (int q = 0; q < 16; ++q) {
        int fi = q * 256 + t;
        int r = fi >> 5, c4 = (fi & 31) * 4;
        int pc4 = c4 ^ (((r >> 2) & 1) << 4);
        float4 v = *(float4*)&Osh[r * 128 + pc4];
        float4 b4 = *(const float4*)&pb[colbase + c4];
        v.x += b4.x; v.y += b4.y; v.z += b4.z; v.w += b4.w;
        *(float4*)&out[(size_t)(m0 + r) * CDIM + colbase + c4] = v;
    }
}

// ---------------- fused 3x3 depthwise conv (bf16 in/out) + BN stats ----------------
__global__ __launch_bounds__(256) void conv3s_kernel(const ushort* __restrict__ Qbf,
                                                     const float* __restrict__ enh_w,
                                                     ushort* __restrict__ QEbf,
                                                     float* __restrict__ ssum,
                                                     float* __restrict__ ssq) {
    const int t = threadIdx.x;
    const int c0 = t * 2;
    const int xpos = blockIdx.x;
    const int byc = blockIdx.y;
    const int b = byc >> 2, yc = byc & 3;
    const int y0 = yc * 14;

    float wgt[9][2];
    #pragma unroll
    for (int tap = 0; tap < 9; ++tap) {
        wgt[tap][0] = enh_w[c0 * 9 + tap];
        wgt[tap][1] = enh_w[(c0 + 1) * 9 + tap];
    }
    const size_t base = (size_t)b * NTOK * CDIM + c0;

    float2 win[3][3];
    auto ldrow = [&](int yy, float2* dst) {
        #pragma unroll
        for (int dx = 0; dx < 3; ++dx) {
            int xx = xpos + dx - 1;
            bool ok = (yy >= 0 && yy < HW && xx >= 0 && xx < HW);
            if (ok) {
                ushort2 uv = *(const ushort2*)(Qbf + base + ((size_t)(yy * HW + xx) << 9));
                dst[dx] = make_float2(bf2f(uv.x), bf2f(uv.y));
            } else {
                dst[dx] = make_float2(0.f, 0.f);
            }
        }
    };
    ldrow(y0 - 1, win[0]);
    ldrow(y0,     win[1]);

    float s1a = 0.f, s2a = 0.f, s1b = 0.f, s2b = 0.f;
    #pragma unroll
    for (int i = 0; i < 14; ++i) {
        int y = y0 + i;
        ldrow(y + 1, win[(i + 2) % 3]);
        float a0 = 0.f, a1 = 0.f;
        #pragma unroll
        for (int dy = 0; dy < 3; ++dy) {
            float2* row = win[(i + dy) % 3];
            #pragma unroll
            for (int dx = 0; dx < 3; ++dx) {
                a0 = fmaf(row[dx].x, wgt[dy * 3 + dx][0], a0);
                a1 = fmaf(row[dx].y, wgt[dy * 3 + dx][1], a1);
            }
        }
        ushort2 o; o.x = f2bf(a0); o.y = f2bf(a1);
        *(ushort2*)(QEbf + base + ((size_t)(y * HW + xpos) << 9)) = o;
        s1a += a0; s2a += a0 * a0;
        s1b += a1; s2b += a1 * a1;
    }
    atomicAdd(&ssum[c0], s1a);     atomicAdd(&ssq[c0], s2a);
    atomicAdd(&ssum[c0 + 1], s1b); atomicAdd(&ssq[c0 + 1], s2b);
}

__global__ void bnprep_kernel(const float* __restrict__ ssum, const float* __restrict__ ssq,
                              const float* __restrict__ bn_g, const float* __restrict__ bn_b,
                              float* __restrict__ achan, float* __restrict__ bchan) {
    int c = threadIdx.x;
    if (c < CDIM) {
        const float invM = 1.0f / (float)MTOT;
        float mean = ssum[c] * invM;
        float var  = ssq[c] * invM - mean * mean;
        float a = bn_g[c] * rsqrtf(var + 1e-5f);
        achan[c] = a;
        bchan[c] = bn_b[c] - mean * a;
    }
}

// ---------------- kvred v4: zero-LDS register MFMA GEMM over KFbf/Vbf ----------
__global__ __launch_bounds__(256) void kvred4_kernel(const ushort* __restrict__ KF,
                                                     const ushort* __restrict__ Vbf,
                                                     float* __restrict__ PKV) {
    const int bh = blockIdx.x, chunk = blockIdx.y;
    const int b = bh >> 3, head = bh & 7;
    const int t = threadIdx.x;
    const int w = t >> 6, l = t & 63;
    const int lr = l & 15;
    const int ns = (l >> 4) * 8;

    const int nbase = b * NTOK + chunk * 448;
    const ushort* kf0 = KF  + ((size_t)(nbase + ns)) * 1024 + head * 128 + (w * 32 + lr);
    const ushort* vb0 = Vbf + ((size_t)(nbase + ns)) * 512  + head * 64  + lr;

    short8 ones;
    #pragma unroll
    for (int j = 0; j < 8; ++j) ones[j] = (lr == 0) ? (short)0x3F80 : (short)0;

    f32x4 acc[2][5] = {};
    for (int tile = 0; tile < 14; ++tile) {
        union { uint u[4]; short8 s; } ua[2], ub[4];
        #pragma unroll
        for (int i = 0; i < 2; ++i) {
            #pragma unroll
            for (int j = 0; j < 4; ++j) {
                uint lo = kf0[i * 16 + (size_t)(2 * j) * 1024];
                uint hi = kf0[i * 16 + (size_t)(2 * j + 1) * 1024];
                ua[i].u[j] = lo | (hi << 16);
            }
        }
        #pragma unroll
        for (int j5 = 0; j5 < 4; ++j5) {
            #pragma unroll
            for (int j = 0; j < 4; ++j) {
                uint lo = vb0[j5 * 16 + (size_t)(2 * j) * 512];
                uint hi = vb0[j5 * 16 + (size_t)(2 * j + 1) * 512];
                ub[j5].u[j] = lo | (hi << 16);
            }
        }
        #pragma unroll
        for (int i = 0; i < 2; ++i) {
            #pragma unroll
            for (int j5 = 0; j5 < 4; ++j5)
                acc[i][j5] = __builtin_amdgcn_mfma_f32_16x16x32_bf16(ua[i].s, ub[j5].s, acc[i][j5], 0, 0, 0);
            acc[i][4] = __builtin_amdgcn_mfma_f32_16x16x32_bf16(ua[i].s, ones, acc[i][4], 0, 0, 0);
        }
        kf0 += (size_t)32 * 1024;
        vb0 += (size_t)32 * 512;
    }
    size_t base = ((size_t)(chunk * 64 + bh)) * 8320;
    #pragma unroll
    for (int i = 0; i < 2; ++i) {
        int d0 = w * 32 + i * 16 + (l >> 4) * 4;
        #pragma unroll
        for (int j = 0; j < 5; ++j) {
            int e = j * 16 + lr;
            if (j < 4 || e == 64)
                *(f32x4*)(PKV + base + (size_t)e * 128 + d0) = acc[i][j];
        }
    }
}

// ---------------- reduce partials -> pre-swizzled bf16 BT image [bh][80][128] ----------------
__global__ __launch_bounds__(256) void kvreduce2_kernel(const float* __restrict__ PKV,
                                                        ushort* __restrict__ kvTbf) {
    int gid = blockIdx.x * 256 + threadIdx.x;   // 64*80*128 = 655360
    const float inv_n = 1.0f / (float)NTOK;
    int bh = gid / 10240;
    int r  = gid - bh * 10240;
    int row = r >> 7, dcol = r & 127;
    int dlog = (((dcol >> 3) ^ (row & 7)) << 3) | (dcol & 7);
    float s = 0.f;
    if (row < 64) {
        int dsel = (row >= 32) ? (dlog ^ 64) : dlog;
        #pragma unroll
        for (int c = 0; c < 7; ++c) s += PKV[(size_t)c * 532480 + (size_t)bh * 8320 + row * 128 + dsel];
    } else if (row < 66) {
        int dsel = (row == 65) ? (dlog ^ 64) : dlog;
        #pragma unroll
        for (int c = 0; c < 7; ++c) s += PKV[(size_t)c * 532480 + (size_t)bh * 8320 + 64 * 128 + dsel];
    }
    kvTbf[gid] = (row < 66) ? f2bf(s * inv_n) : (ushort)0;
}

// ---------------- attention apply via MFMA (qfin fused), bf16 Q/QE in, bf16 out -------
__global__ __launch_bounds__(256) void attn_mfma_kernel(const ushort* __restrict__ Qbf,
                                                        const ushort* __restrict__ QEbf,
                                                        const ushort* __restrict__ kvTbf,
                                                        const float* __restrict__ power,
                                                        const float* __restrict__ achan,
                                                        const float* __restrict__ bchan,
                                                        const float* __restrict__ invs,
                                                        const float* __restrict__ ewp,
                                                        ushort* __restrict__ ATTbf) {
    __shared__ ushort QF[64 * 128];
    __shared__ ushort BT[80 * 128];
    const int bh = blockIdx.x, tb = blockIdx.y;
    const int b = bh >> 3, head = bh & 7;
    const int t = threadIdx.x;
    const int w = t >> 6, l = t & 63;

    #pragma unroll
    for (int i = 0; i < 5; ++i) {
        int f = i * 256 + t;
        gload_lds16(kvTbf + (size_t)bh * 10240 + f * 8, BT + f * 8);
    }

    const int c = l, hc = head * 64 + c;
    const float p = power[hc];
    const float ac = achan[hc], bc = bchan[hc], iv = invs[hc], ew = ewp[0];
    #pragma unroll
    for (int i = 0; i < 16; ++i) {
        int tok = i * 4 + w;
        size_t off = ((size_t)(b * NTOK + tb * 64 + tok)) * CDIM + hc;
        float q = bf2f(Qbf[off]);
        float qe = bf2f(QEbf[off]);
        q = (q + ew * fmaxf(fmaf(ac, qe, bc), 0.f)) * iv;
        float ax = fabsf(q);
        float tp = ax > 0.f ? __powf(ax, p) : 0.f;
        float qp = q > 0.f ? tp : 0.f;
        float qn = q < 0.f ? tp : 0.f;
        int sw = tok & 7;
        QF[tok * 128 + (((c >> 3) ^ sw) * 8) + (c & 7)]       = f2bf(qp);
        QF[tok * 128 + ((((c >> 3) + 8) ^ sw) * 8) + (c & 7)] = f2bf(qn);
    }
    __syncthreads();

    f32x4 acc[5] = {};
    #pragma unroll
    for (int kk = 0; kk < 4; ++kk) {
        int sbase = kk * 4 + (l >> 4);
        int rowa = w * 16 + (l & 15);
        short8 af = *(const short8*)&QF[rowa * 128 + ((sbase ^ (rowa & 7)) * 8)];
        #pragma unroll
        for (int j = 0; j < 5; ++j) {
            int rowb = j * 16 + (l & 15);
            short8 bf = *(const short8*)&BT[rowb * 128 + ((sbase ^ (rowb & 7)) * 8)];
            acc[j] = __builtin_amdgcn_mfma_f32_16x16x32_bf16(af, bf, acc[j], 0, 0, 0);
        }
    }
    __syncthreads();

    ushort* Oout = QF;
    #pragma unroll
    for (int rr = 0; rr < 4; ++rr) {
        float ssim = __shfl(acc[4][rr], (l & 48));
        float sopp = __shfl(acc[4][rr], (l & 48) + 1);
        float zs = 1.f / (ssim + 1e-6f);
        float zo = 1.f / (sopp + 1e-6f);
        int tokl = w * 16 + (l >> 4) * 4 + rr;
        #pragma unroll
        for (int j = 0; j < 4; ++j) {
            int e = j * 16 + (l & 15);
            Oout[tokl * 64 + e] = f2bf(acc[j][rr] * (j < 2 ? zs : zo));
        }
    }
    __syncthreads();

    #pragma unroll
    for (int i = 0; i < 2; ++i) {
        int idx = i * 256 + t;
        int tokl = idx >> 3, ch = (idx & 7) * 8;
        short8 vv = *(short8*)&Oout[tokl * 64 + ch];
        *(short8*)&ATTbf[((size_t)(b * NTOK + tb * 64 + tokl)) * CDIM + head * 64 + ch] = vv;
    }
}

// ---------------- v 5x5 depthwise conv (bf16 V) + gate (bf16 ATT, bf16 G) --------------
__global__ __launch_bounds__(256) void voutg2_kernel(const ushort* __restrict__ Vbf,
                                                     const ushort* __restrict__ ATTbf,
                                                     const ushort* __restrict__ Gbf,
                                                     const float* __restrict__ dwc_w,
                                                     const float* __restrict__ dwc_b,
                                                     ushort* __restrict__ PRE) {
    const int t = threadIdx.x;
    const int c0 = t * 2;
    const int xpos = blockIdx.x;
    const int byc = blockIdx.y;
    const int b = byc >> 2, yc = byc & 3;
    const int y0 = yc * 14;
    const int dch = c0 & 63;

    float wgt[25][2];
    #pragma unroll
    for (int tap = 0; tap < 25; ++tap) {
        wgt[tap][0] = dwc_w[dch * 25 + tap];
        wgt[tap][1] = dwc_w[(dch + 1) * 25 + tap];
    }
    const float bias0 = dwc_b[dch], bias1 = dwc_b[dch + 1];
    const size_t base = (size_t)b * NTOK * CDIM + c0;

    float2 win[5][5];
    auto ldrow = [&](int yy, float2* dst) {
        #pragma unroll
        for (int dx = 0; dx < 5; ++dx) {
            int xx = xpos + dx - 2;
            bool ok = (yy >= 0 && yy < HW && xx >= 0 && xx < HW);
            if (ok) {
                ushort2 uv = *(const ushort2*)(Vbf + base + ((size_t)(yy * HW + xx) << 9));
                dst[dx] = make_float2(bf2f(uv.x), bf2f(uv.y));
            } else {
                dst[dx] = make_float2(0.f, 0.f);
            }
        }
    };
    ldrow(y0 - 2, win[0]);
    ldrow(y0 - 1, win[1]);
    ldrow(y0,     win[2]);
    ldrow(y0 + 1, win[3]);

    #pragma unroll
    for (int i = 0; i < 14; ++i) {
        int y = y0 + i;
        ldrow(y + 2, win[(i + 4) % 5]);
        float a0 = bias0, a1 = bias1;
        #pragma unroll
        for (int dy = 0; dy < 5; ++dy) {
            float2* row = win[(i + dy) % 5];
            #pragma unroll
            for (int dx = 0; dx < 5; ++dx) {
                a0 = fmaf(row[dx].x, wgt[dy * 5 + dx][0], a0);
                a1 = fmaf(row[dx].y, wgt[dy * 5 + dx][1], a1);
            }
        }
        size_t oidx = base + ((size_t)(y * HW + xpos) << 9);
        ushort2 au = *(const ushort2*)(ATTbf + oidx);
        ushort2 gu = *(const ushort2*)(Gbf + oidx);
        ushort2 o;
        o.x = f2bf((bf2f(au.x) + a0) * bf2f(gu.x));
        o.y = f2bf((bf2f(au.y) + a1) * bf2f(gu.y));
        *(ushort2*)(PRE + oidx) = o;
    }
}

extern "C" void kernel_launch(void* const* d_in, const int* in_sizes, int n_in,
                              void* d_out, int out_size, void* d_ws, size_t ws_size,
                              hipStream_t stream) {
    const float* x      = (const float*)d_in[0];
    const float* qg_w   = (const float*)d_in[1];
    const float* kv_w   = (const float*)d_in[2];
    const float* proj_w = (const float*)d_in[3];
    const float* proj_b = (const float*)d_in[4];
    const float* dwc_w  = (const float*)d_in[5];
    const float* dwc_b  = (const float*)d_in[6];
    const float* power_p= (const float*)d_in[7];
    const float* scale_p= (const float*)d_in[8];
    const float* enh_w  = (const float*)d_in[9];
    const float* bn_g   = (const float*)d_in[10];
    const float* bn_b   = (const float*)d_in[11];
    const float* ew_p   = (const float*)d_in[12];
    const float* pos    = (const float*)d_in[13];

    const size_t NELEM = (size_t)MTOT * CDIM;   // 12,845,056
    float* ws    = (float*)d_ws;
    ushort* Qbf  = (ushort*)ws;
    ushort* Gbf  = (ushort*)(ws + NELEM);
    float*  PKV  = ws + NELEM + NELEM / 2;
    ushort* KFbf = (ushort*)(ws + 2 * NELEM);
    ushort* PREbf= (ushort*)(ws + 2 * NELEM);
    ushort* Vbf  = (ushort*)(ws + 3 * NELEM);
    ushort* ATTbf= (ushort*)(ws + 3 * NELEM + NELEM / 2);
    ushort* Xbf  = (ushort*)(ws + 4 * NELEM);
    ushort* QEbf = (ushort*)(ws + 4 * NELEM);
    float* SMALL = ws + 5 * NELEM;
    float* ssum  = SMALL;               // 512
    float* ssq   = SMALL + 512;         // 512
    ushort* kvTbf= (ushort*)(SMALL + 9216);      // 655,360 ushorts
    float* invs  = SMALL + 533504;
    float* powr  = SMALL + 534016;
    float* achan = SMALL + 534528;
    float* bchan = SMALL + 535040;
    ushort* Wqg  = (ushort*)(SMALL + 535552);
    ushort* Wkv  = (ushort*)(SMALL + 797696);
    ushort* Wproj= (ushort*)(SMALL + 1059840);

    hipMemsetAsync(SMALL, 0, (size_t)1024 * sizeof(float), stream);

    prep_kernel<<<1, 512, 0, stream>>>(scale_p, power_p, invs, powr);

    cvt_bf16_kernel<<<12544, 256, 0, stream>>>(x, Xbf, 3211264);
    cvt_weights_kernel<<<1280, 256, 0, stream>>>(qg_w, kv_w, proj_w, Wqg, Wkv, Wproj);

    mgemm_qgkv<<<3136, 256, 0, stream>>>(Xbf, Wqg, Wkv, Qbf, Gbf, KFbf, Vbf, pos, invs, powr);

    dim3 cgrid(56, 32);
    conv3s_kernel<<<cgrid, 256, 0, stream>>>(Qbf, enh_w, QEbf, ssum, ssq);
    bnprep_kernel<<<1, 512, 0, stream>>>(ssum, ssq, bn_g, bn_b, achan, bchan);

    kvred4_kernel<<<dim3(64, 7), 256, 0, stream>>>(KFbf, Vbf, PKV);
    kvreduce2_kernel<<<2560, 256, 0, stream>>>(PKV, kvTbf);

    attn_mfma_kernel<<<dim3(64, 49), 256, 0, stream>>>(Qbf, QEbf, kvTbf, powr,
                                                       achan, bchan, invs, ew_p, ATTbf);

    voutg2_kernel<<<cgrid, 256, 0, stream>>>(Vbf, ATTbf, Gbf, dwc_w, dwc_b, PREbf);

    mgemm_proj<<<784, 256, 0, stream>>>(PREbf, Wproj, (float*)d_out, proj_b);
}

// Round 15
// 481.867 us; speedup vs baseline: 1.1229x; 1.1229x over previous
//
#include <hip/hip_runtime.h>
#include <hip/hip_bf16.h>
#include <math.h>

#define CDIM 512
#define NTOK 3136
#define BATCH 8
#define MTOT (BATCH*NTOK)   // 25088
#define NHEAD 8
#define DHEAD 64
#define HW 56

typedef __attribute__((ext_vector_type(8))) short short8;
typedef __attribute__((ext_vector_type(4))) float f32x4;

__device__ __forceinline__ ushort f2bf(float f) {
    union { float f; unsigned int u; } v; v.f = f;
    unsigned int u = v.u + 0x7FFFu + ((v.u >> 16) & 1u);
    return (ushort)(u >> 16);
}
__device__ __forceinline__ float bf2f(ushort u) {
    union { unsigned int u; float f; } v; v.u = ((unsigned int)u) << 16;
    return v.f;
}

__device__ __forceinline__ void gload_lds16(const void* g, void* lds) {
    __builtin_amdgcn_global_load_lds((const __attribute__((address_space(1))) void*)g,
                                     (__attribute__((address_space(3))) void*)lds,
                                     16, 0, 0);
}

// ---------------- prep ----------------
__global__ void prep_kernel(const float* __restrict__ scale_p,
                            const float* __restrict__ power_p,
                            float* __restrict__ inv_scale,
                            float* __restrict__ power) {
    int c = threadIdx.x;
    if (c < CDIM) {
        float s = log1pf(expf(scale_p[c]));
        inv_scale[c] = 1.0f / s;
        power[c] = 1.0f + 4.0f / (1.0f + expf(-power_p[c]));
    }
}

__global__ __launch_bounds__(256) void cvt_bf16_kernel(const float* __restrict__ src,
                                                       ushort* __restrict__ dst, int n4) {
    int i = blockIdx.x * 256 + threadIdx.x;
    if (i < n4) {
        float4 f = ((const float4*)src)[i];
        ushort4 o;
        o.x = f2bf(f.x); o.y = f2bf(f.y); o.z = f2bf(f.z); o.w = f2bf(f.w);
        ((ushort4*)dst)[i] = o;
    }
}

// all three weight conversions in one launch
__global__ __launch_bounds__(256) void cvt_weights_kernel(const float* __restrict__ qg_w,
                                                          const float* __restrict__ kv_w,
                                                          const float* __restrict__ proj_w,
                                                          ushort* __restrict__ Wqg,
                                                          ushort* __restrict__ Wkv,
                                                          ushort* __restrict__ Wproj) {
    int i = blockIdx.x * 256 + threadIdx.x;
    const float* src; ushort* dst; int idx;
    if (i < 131072)      { src = qg_w;   dst = Wqg;   idx = i; }
    else if (i < 262144) { src = kv_w;   dst = Wkv;   idx = i - 131072; }
    else                 { src = proj_w; dst = Wproj; idx = i - 262144; }
    float4 f = ((const float4*)src)[idx];
    ushort4 o;
    o.x = f2bf(f.x); o.y = f2bf(f.y); o.z = f2bf(f.z); o.w = f2bf(f.w);
    ((ushort4*)dst)[idx] = o;
}

// ---------------- merged qg+kv GEMM: dbuf BK=64 (0-conflict), XOR epilogue.
// Q fp32 out; G/KF/V bf16. grid 3136; idp=(bid&7)*392+(bid>>3); mb=idp>>4, ob=idp&15.
__global__ __launch_bounds__(256) void mgemm_qgkv(const ushort* __restrict__ A,
                                                  const ushort* __restrict__ Wqg,
                                                  const ushort* __restrict__ Wkv,
                                                  float* __restrict__ Qout,
                                                  ushort* __restrict__ Gout,
                                                  ushort* __restrict__ KFout,
                                                  ushort* __restrict__ Vout,
                                                  const float* __restrict__ pos,
                                                  const float* __restrict__ invs,
                                                  const float* __restrict__ powr) {
    __shared__ __align__(16) char smem[65536];
    ushort* At = (ushort*)smem;               // [2][128*64]
    ushort* Bt = (ushort*)(smem + 32768);     // [2][128*64]
    float*  Osh = (float*)smem;               // epilogue alias [128][128]

    const int t = threadIdx.x;
    const int w = t >> 6, l = t & 63;
    const int wr = w >> 1, wc = w & 1;
    const int r8 = l >> 3, sl = l & 7;
    const int ss = sl ^ r8;

    const int bid = blockIdx.x;
    const int idp = (bid & 7) * 392 + (bid >> 3);
    const int mb = idp >> 4, ob = idp & 15;
    const int m0 = mb * 128;
    const ushort* Bp = (ob < 8) ? (Wqg + (size_t)ob * 128 * CDIM)
                                : (Wkv + (size_t)(ob - 8) * 128 * CDIM);

    auto stage = [&](int buf, int ks) {
        const int k0 = ks * 64;
        #pragma unroll
        for (int c = 0; c < 4; ++c) {
            int rc = (w * 4 + c) * 8 + r8;
            gload_lds16(A + (size_t)(m0 + rc) * CDIM + k0 + ss * 8, At + buf * 8192 + (w * 4 + c) * 512);
            gload_lds16(Bp + (size_t)rc * CDIM + k0 + ss * 8, Bt + buf * 8192 + (w * 4 + c) * 512);
        }
    };

    f32x4 acc[4][4] = {};
    stage(0, 0);
    __syncthreads();
    for (int ks = 0; ks < 8; ++ks) {
        int cur = ks & 1;
        if (ks < 7) stage(cur ^ 1, ks + 1);
        #pragma unroll
        for (int kk = 0; kk < 2; ++kk) {
            short8 af[4], bfr[4];
            const int sbase = kk * 4 + (l >> 4);
            #pragma unroll
            for (int i = 0; i < 4; ++i) {
                int row = wr * 64 + i * 16 + (l & 15);
                af[i] = *(const short8*)&At[cur * 8192 + row * 64 + ((sbase ^ (row & 7)) * 8)];
                int rowb = wc * 64 + i * 16 + (l & 15);
                bfr[i] = *(const short8*)&Bt[cur * 8192 + rowb * 64 + ((sbase ^ (rowb & 7)) * 8)];
            }
            #pragma unroll
            for (int i = 0; i < 4; ++i)
                #pragma unroll
                for (int j = 0; j < 4; ++j)
                    acc[i][j] = __builtin_amdgcn_mfma_f32_16x16x32_bf16(af[i], bfr[j], acc[i][j], 0, 0, 0);
        }
        __syncthreads();
    }

    // acc -> Osh with bit4-column-XOR (write 2-way=free, read conflict-free)
    #pragma unroll
    for (int i = 0; i < 4; ++i)
        #pragma unroll
        for (int j = 0; j < 4; ++j)
            #pragma unroll
            for (int rr = 0; rr < 4; ++rr) {
                int row = wr * 64 + i * 16 + (l >> 4) * 4 + rr;
                int col = wc * 64 + j * 16 + (l & 15);
                int pc = col ^ (((row >> 2) & 1) << 4);
                Osh[row * 128 + pc] = acc[i][j][rr];
            }
    __syncthreads();

    const int colbase = ob * 128;
    #pragma unroll
    for (int q = 0; q < 16; ++q) {
        int fi = q * 256 + t;
        int r = fi >> 5, c4 = (fi & 31) * 4;
        int pc4 = c4 ^ (((r >> 2) & 1) << 4);
        float4 v = *(float4*)&Osh[r * 128 + pc4];
        int m = m0 + r;
        if (colbase < 512) {
            *(float4*)&Qout[(size_t)m * CDIM + colbase + c4] = v;
        } else if (colbase < 1024) {
            ushort4 o;
            o.x = f2bf(v.x); o.y = f2bf(v.y); o.z = f2bf(v.z); o.w = f2bf(v.w);
            *(ushort4*)&Gout[(size_t)m * CDIM + colbase - 512 + c4] = o;
        } else if (colbase < 1536) {
            int n = m % NTOK;
            int oc = colbase - 1024 + c4;
            float4 pv = *(const float4*)&pos[(size_t)n * CDIM + oc];
            float4 iv = *(const float4*)&invs[oc];
            float4 pw = *(const float4*)&powr[oc];
            float kx0 = (v.x + pv.x) * iv.x, kx1 = (v.y + pv.y) * iv.y;
            float kx2 = (v.z + pv.z) * iv.z, kx3 = (v.w + pv.w) * iv.w;
            float t0 = __powf(fabsf(kx0), pw.x), t1 = __powf(fabsf(kx1), pw.y);
            float t2 = __powf(fabsf(kx2), pw.z), t3 = __powf(fabsf(kx3), pw.w);
            ushort4 up, un;
            up.x = kx0 > 0.f ? f2bf(t0) : 0; un.x = kx0 < 0.f ? f2bf(t0) : 0;
            up.y = kx1 > 0.f ? f2bf(t1) : 0; un.y = kx1 < 0.f ? f2bf(t1) : 0;
            up.z = kx2 > 0.f ? f2bf(t2) : 0; un.z = kx2 < 0.f ? f2bf(t2) : 0;
            up.w = kx3 > 0.f ? f2bf(t3) : 0; un.w = kx3 < 0.f ? f2bf(t3) : 0;
            ushort* dst = KFout + (size_t)m * 1024 + ((oc >> 6) << 7) + (oc & 63);
            *(ushort4*)dst = up;
            *(ushort4*)(dst + 64) = un;
        } else {
            ushort4 o;
            o.x = f2bf(v.x); o.y = f2bf(v.y); o.z = f2bf(v.z); o.w = f2bf(v.w);
            *(ushort4*)&Vout[(size_t)m * CDIM + colbase - 1536 + c4] = o;
        }
    }
}

// ---------------- proj GEMM: dbuf BK=64, XOR fp32 epilogue ----------------
__global__ __launch_bounds__(256) void mgemm_proj(const ushort* __restrict__ A,
                                                  const ushort* __restrict__ W,
                                                  float* __restrict__ out,
                                                  const float* __restrict__ pb) {
    __shared__ __align__(16) char smem[65536];
    ushort* At = (ushort*)smem;
    ushort* Bt = (ushort*)(smem + 32768);
    float*  Osh = (float*)smem;

    const int t = threadIdx.x;
    const int w = t >> 6, l = t & 63;
    const int wr = w >> 1, wc = w & 1;
    const int r8 = l >> 3, sl = l & 7;
    const int ss = sl ^ r8;

    const int bid = blockIdx.x;
    const int idp = (bid & 7) * 98 + (bid >> 3);
    const int mb = idp >> 2, ob = idp & 3;
    const int m0 = mb * 128;
    const ushort* Bp = W + (size_t)ob * 128 * CDIM;

    auto stage = [&](int buf, int ks) {
        const int k0 = ks * 64;
        #pragma unroll
        for (int c = 0; c < 4; ++c) {
            int rc = (w * 4 + c) * 8 + r8;
            gload_lds16(A + (size_t)(m0 + rc) * CDIM + k0 + ss * 8, At + buf * 8192 + (w * 4 + c) * 512);
            gload_lds16(Bp + (size_t)rc * CDIM + k0 + ss * 8, Bt + buf * 8192 + (w * 4 + c) * 512);
        }
    };

    f32x4 acc[4][4] = {};
    stage(0, 0);
    __syncthreads();
    for (int ks = 0; ks < 8; ++ks) {
        int cur = ks & 1;
        if (ks < 7) stage(cur ^ 1, ks + 1);
        #pragma unroll
        for (int kk = 0; kk < 2; ++kk) {
            short8 af[4], bfr[4];
            const int sbase = kk * 4 + (l >> 4);
            #pragma unroll
            for (int i = 0; i < 4; ++i) {
                int row = wr * 64 + i * 16 + (l & 15);
                af[i] = *(const short8*)&At[cur * 8192 + row * 64 + ((sbase ^ (row & 7)) * 8)];
                int rowb = wc * 64 + i * 16 + (l & 15);
                bfr[i] = *(const short8*)&Bt[cur * 8192 + rowb * 64 + ((sbase ^ (rowb & 7)) * 8)];
            }
            #pragma unroll
            for (int i = 0; i < 4; ++i)
                #pragma unroll
                for (int j = 0; j < 4; ++j)
                    acc[i][j] = __builtin_amdgcn_mfma_f32_16x16x32_bf16(af[i], bfr[j], acc[i][j], 0, 0, 0);
        }
        __syncthreads();
    }

    #pragma unroll
    for (int i = 0; i < 4; ++i)
        #pragma unroll
        for (int j = 0; j < 4; ++j)
            #pragma unroll
            for (int rr = 0; rr < 4; ++rr) {
                int row = wr * 64 + i * 16 + (l >> 4) * 4 + rr;
                int col = wc * 64 + j * 16 + (l & 15);
                int pc = col ^ (((row >> 2) & 1) << 4);
                Osh[row * 128 + pc] = acc[i][j][rr];
            }
    __syncthreads();

    const int colbase = ob * 128;
    #pragma unroll
    for (int q = 0; q < 16; ++q) {
        int fi = q * 256 + t;
        int r = fi >> 5, c4 = (fi & 31) * 4;
        int pc4 = c4 ^ (((r >> 2) & 1) << 4);
        float4 v = *(float4*)&Osh[r * 128 + pc4];
        float4 b4 = *(const float4*)&pb[colbase + c4];
        v.x += b4.x; v.y += b4.y; v.z += b4.z; v.w += b4.w;
        *(float4*)&out[(size_t)(m0 + r) * CDIM + colbase + c4] = v;
    }
}

// ---------------- fused 3x3 depthwise conv (fp32 Q in, bf16 QE out) + BN stats -------
__global__ __launch_bounds__(256) void conv3s_kernel(const float* __restrict__ Q,
                                                     const float* __restrict__ enh_w,
                                                     ushort* __restrict__ QEbf,
                                                     float* __restrict__ ssum,
                                                     float* __restrict__ ssq) {
    const int t = threadIdx.x;
    const int c0 = t * 2;
    const int xpos = blockIdx.x;
    const int byc = blockIdx.y;
    const int b = byc >> 2, yc = byc & 3;
    const int y0 = yc * 14;

    float wgt[9][2];
    #pragma unroll
    for (int tap = 0; tap < 9; ++tap) {
        wgt[tap][0] = enh_w[c0 * 9 + tap];
        wgt[tap][1] = enh_w[(c0 + 1) * 9 + tap];
    }
    const size_t base = (size_t)b * NTOK * CDIM + c0;

    float2 win[3][3];
    auto ldrow = [&](int yy, float2* dst) {
        #pragma unroll
        for (int dx = 0; dx < 3; ++dx) {
            int xx = xpos + dx - 1;
            bool ok = (yy >= 0 && yy < HW && xx >= 0 && xx < HW);
            dst[dx] = ok ? *(const float2*)(Q + base + ((size_t)(yy * HW + xx) << 9))
                         : make_float2(0.f, 0.f);
        }
    };
    ldrow(y0 - 1, win[0]);
    ldrow(y0,     win[1]);

    float s1a = 0.f, s2a = 0.f, s1b = 0.f, s2b = 0.f;
    #pragma unroll
    for (int i = 0; i < 14; ++i) {
        int y = y0 + i;
        ldrow(y + 1, win[(i + 2) % 3]);
        float a0 = 0.f, a1 = 0.f;
        #pragma unroll
        for (int dy = 0; dy < 3; ++dy) {
            float2* row = win[(i + dy) % 3];
            #pragma unroll
            for (int dx = 0; dx < 3; ++dx) {
                a0 = fmaf(row[dx].x, wgt[dy * 3 + dx][0], a0);
                a1 = fmaf(row[dx].y, wgt[dy * 3 + dx][1], a1);
            }
        }
        ushort2 o; o.x = f2bf(a0); o.y = f2bf(a1);
        *(ushort2*)(QEbf + base + ((size_t)(y * HW + xpos) << 9)) = o;
        s1a += a0; s2a += a0 * a0;
        s1b += a1; s2b += a1 * a1;
    }
    atomicAdd(&ssum[c0], s1a);     atomicAdd(&ssq[c0], s2a);
    atomicAdd(&ssum[c0 + 1], s1b); atomicAdd(&ssq[c0 + 1], s2b);
}

__global__ void bnprep_kernel(const float* __restrict__ ssum, const float* __restrict__ ssq,
                              const float* __restrict__ bn_g, const float* __restrict__ bn_b,
                              float* __restrict__ achan, float* __restrict__ bchan) {
    int c = threadIdx.x;
    if (c < CDIM) {
        const float invM = 1.0f / (float)MTOT;
        float mean = ssum[c] * invM;
        float var  = ssq[c] * invM - mean * mean;
        float a = bn_g[c] * rsqrtf(var + 1e-5f);
        achan[c] = a;
        bchan[c] = bn_b[c] - mean * a;
    }
}

// ---------------- kvred v4: zero-LDS register MFMA GEMM, 14 chunks, split PKV --------
__global__ __launch_bounds__(256) void kvred4_kernel(const ushort* __restrict__ KF,
                                                     const ushort* __restrict__ Vbf,
                                                     float* __restrict__ PKV_A,
                                                     float* __restrict__ PKV_B) {
    const int bh = blockIdx.x, chunk = blockIdx.y;   // chunk 0..13
    const int b = bh >> 3, head = bh & 7;
    const int t = threadIdx.x;
    const int w = t >> 6, l = t & 63;
    const int lr = l & 15;
    const int ns = (l >> 4) * 8;

    const int nbase = b * NTOK + chunk * 224;
    const ushort* kf0 = KF  + ((size_t)(nbase + ns)) * 1024 + head * 128 + (w * 32 + lr);
    const ushort* vb0 = Vbf + ((size_t)(nbase + ns)) * 512  + head * 64  + lr;

    short8 ones;
    #pragma unroll
    for (int j = 0; j < 8; ++j) ones[j] = (lr == 0) ? (short)0x3F80 : (short)0;

    f32x4 acc[2][5] = {};
    for (int tile = 0; tile < 7; ++tile) {
        union { uint u[4]; short8 s; } ua[2], ub[4];
        #pragma unroll
        for (int i = 0; i < 2; ++i) {
            #pragma unroll
            for (int j = 0; j < 4; ++j) {
                uint lo = kf0[i * 16 + (size_t)(2 * j) * 1024];
                uint hi = kf0[i * 16 + (size_t)(2 * j + 1) * 1024];
                ua[i].u[j] = lo | (hi << 16);
            }
        }
        #pragma unroll
        for (int j5 = 0; j5 < 4; ++j5) {
            #pragma unroll
            for (int j = 0; j < 4; ++j) {
                uint lo = vb0[j5 * 16 + (size_t)(2 * j) * 512];
                uint hi = vb0[j5 * 16 + (size_t)(2 * j + 1) * 512];
                ub[j5].u[j] = lo | (hi << 16);
            }
        }
        #pragma unroll
        for (int i = 0; i < 2; ++i) {
            #pragma unroll
            for (int j5 = 0; j5 < 4; ++j5)
                acc[i][j5] = __builtin_amdgcn_mfma_f32_16x16x32_bf16(ua[i].s, ub[j5].s, acc[i][j5], 0, 0, 0);
            acc[i][4] = __builtin_amdgcn_mfma_f32_16x16x32_bf16(ua[i].s, ones, acc[i][4], 0, 0, 0);
        }
        kf0 += (size_t)32 * 1024;
        vb0 += (size_t)32 * 512;
    }
    float* dstb = (chunk < 7)
        ? (PKV_A + ((size_t)(chunk * 64 + bh)) * 8320)
        : (PKV_B + ((size_t)((chunk - 7) * 64 + bh)) * 8320);
    #pragma unroll
    for (int i = 0; i < 2; ++i) {
        int d0 = w * 32 + i * 16 + (l >> 4) * 4;
        #pragma unroll
        for (int j = 0; j < 5; ++j) {
            int e = j * 16 + lr;
            if (j < 4 || e == 64)
                *(f32x4*)(dstb + (size_t)e * 128 + d0) = acc[i][j];
        }
    }
}

// ---------------- reduce split partials -> pre-swizzled bf16 BT image [bh][80][128] -----
__global__ __launch_bounds__(256) void kvreduce2_kernel(const float* __restrict__ PKV_A,
                                                        const float* __restrict__ PKV_B,
                                                        ushort* __restrict__ kvTbf) {
    int gid = blockIdx.x * 256 + threadIdx.x;   // 64*80*128 = 655360
    const float inv_n = 1.0f / (float)NTOK;
    int bh = gid / 10240;
    int r  = gid - bh * 10240;
    int row = r >> 7, dcol = r & 127;
    int dlog = (((dcol >> 3) ^ (row & 7)) << 3) | (dcol & 7);
    float s = 0.f;
    if (row < 66) {
        int rsel, dsel;
        if (row < 64) { rsel = row; dsel = (row >= 32) ? (dlog ^ 64) : dlog; }
        else          { rsel = 64;  dsel = (row == 65) ? (dlog ^ 64) : dlog; }
        size_t idx = (size_t)bh * 8320 + rsel * 128 + dsel;
        #pragma unroll
        for (int c = 0; c < 7; ++c) s += PKV_A[(size_t)c * 532480 + idx];
        #pragma unroll
        for (int c = 0; c < 7; ++c) s += PKV_B[(size_t)c * 532480 + idx];
    }
    kvTbf[gid] = (row < 66) ? f2bf(s * inv_n) : (ushort)0;
}

// ---------------- attention apply via MFMA (qfin fused), fp32 Q + bf16 QE in --------
__global__ __launch_bounds__(256) void attn_mfma_kernel(const float* __restrict__ Q,
                                                        const ushort* __restrict__ QEbf,
                                                        const ushort* __restrict__ kvTbf,
                                                        const float* __restrict__ power,
                                                        const float* __restrict__ achan,
                                                        const float* __restrict__ bchan,
                                                        const float* __restrict__ invs,
                                                        const float* __restrict__ ewp,
                                                        ushort* __restrict__ ATTbf) {
    __shared__ ushort QF[64 * 128];
    __shared__ ushort BT[80 * 128];
    const int bh = blockIdx.x, tb = blockIdx.y;
    const int b = bh >> 3, head = bh & 7;
    const int t = threadIdx.x;
    const int w = t >> 6, l = t & 63;

    #pragma unroll
    for (int i = 0; i < 5; ++i) {
        int f = i * 256 + t;
        gload_lds16(kvTbf + (size_t)bh * 10240 + f * 8, BT + f * 8);
    }

    const int c = l, hc = head * 64 + c;
    const float p = power[hc];
    const float ac = achan[hc], bc = bchan[hc], iv = invs[hc], ew = ewp[0];
    #pragma unroll
    for (int i = 0; i < 16; ++i) {
        int tok = i * 4 + w;
        size_t off = ((size_t)(b * NTOK + tb * 64 + tok)) * CDIM + hc;
        float q = Q[off];
        float qe = bf2f(QEbf[off]);
        q = (q + ew * fmaxf(fmaf(ac, qe, bc), 0.f)) * iv;
        float ax = fabsf(q);
        float tp = ax > 0.f ? __powf(ax, p) : 0.f;
        float qp = q > 0.f ? tp : 0.f;
        float qn = q < 0.f ? tp : 0.f;
        int sw = tok & 7;
        QF[tok * 128 + (((c >> 3) ^ sw) * 8) + (c & 7)]       = f2bf(qp);
        QF[tok * 128 + ((((c >> 3) + 8) ^ sw) * 8) + (c & 7)] = f2bf(qn);
    }
    __syncthreads();

    f32x4 acc[5] = {};
    #pragma unroll
    for (int kk = 0; kk < 4; ++kk) {
        int sbase = kk * 4 + (l >> 4);
        int rowa = w * 16 + (l & 15);
        short8 af = *(const short8*)&QF[rowa * 128 + ((sbase ^ (rowa & 7)) * 8)];
        #pragma unroll
        for (int j = 0; j < 5; ++j) {
            int rowb = j * 16 + (l & 15);
            short8 bf = *(const short8*)&BT[rowb * 128 + ((sbase ^ (rowb & 7)) * 8)];
            acc[j] = __builtin_amdgcn_mfma_f32_16x16x32_bf16(af, bf, acc[j], 0, 0, 0);
        }
    }
    __syncthreads();

    ushort* Oout = QF;
    #pragma unroll
    for (int rr = 0; rr < 4; ++rr) {
        float ssim = __shfl(acc[4][rr], (l & 48));
        float sopp = __shfl(acc[4][rr], (l & 48) + 1);
        float zs = 1.f / (ssim + 1e-6f);
        float zo = 1.f / (sopp + 1e-6f);
        int tokl = w * 16 + (l >> 4) * 4 + rr;
        #pragma unroll
        for (int j = 0; j < 4; ++j) {
            int e = j * 16 + (l & 15);
            Oout[tokl * 64 + e] = f2bf(acc[j][rr] * (j < 2 ? zs : zo));
        }
    }
    __syncthreads();

    #pragma unroll
    for (int i = 0; i < 2; ++i) {
        int idx = i * 256 + t;
        int tokl = idx >> 3, ch = (idx & 7) * 8;
        short8 vv = *(short8*)&Oout[tokl * 64 + ch];
        *(short8*)&ATTbf[((size_t)(b * NTOK + tb * 64 + tokl)) * CDIM + head * 64 + ch] = vv;
    }
}

// ---------------- v 5x5 depthwise conv (bf16 V) + gate (bf16 ATT, bf16 G) --------------
__global__ __launch_bounds__(256) void voutg2_kernel(const ushort* __restrict__ Vbf,
                                                     const ushort* __restrict__ ATTbf,
                                                     const ushort* __restrict__ Gbf,
                                                     const float* __restrict__ dwc_w,
                                                     const float* __restrict__ dwc_b,
                                                     ushort* __restrict__ PRE) {
    const int t = threadIdx.x;
    const int c0 = t * 2;
    const int xpos = blockIdx.x;
    const int byc = blockIdx.y;
    const int b = byc >> 2, yc = byc & 3;
    const int y0 = yc * 14;
    const int dch = c0 & 63;

    float wgt[25][2];
    #pragma unroll
    for (int tap = 0; tap < 25; ++tap) {
        wgt[tap][0] = dwc_w[dch * 25 + tap];
        wgt[tap][1] = dwc_w[(dch + 1) * 25 + tap];
    }
    const float bias0 = dwc_b[dch], bias1 = dwc_b[dch + 1];
    const size_t base = (size_t)b * NTOK * CDIM + c0;

    float2 win[5][5];
    auto ldrow = [&](int yy, float2* dst) {
        #pragma unroll
        for (int dx = 0; dx < 5; ++dx) {
            int xx = xpos + dx - 2;
            bool ok = (yy >= 0 && yy < HW && xx >= 0 && xx < HW);
            if (ok) {
                ushort2 uv = *(const ushort2*)(Vbf + base + ((size_t)(yy * HW + xx) << 9));
                dst[dx] = make_float2(bf2f(uv.x), bf2f(uv.y));
            } else {
                dst[dx] = make_float2(0.f, 0.f);
            }
        }
    };
    ldrow(y0 - 2, win[0]);
    ldrow(y0 - 1, win[1]);
    ldrow(y0,     win[2]);
    ldrow(y0 + 1, win[3]);

    #pragma unroll
    for (int i = 0; i < 14; ++i) {
        int y = y0 + i;
        ldrow(y + 2, win[(i + 4) % 5]);
        float a0 = bias0, a1 = bias1;
        #pragma unroll
        for (int dy = 0; dy < 5; ++dy) {
            float2* row = win[(i + dy) % 5];
            #pragma unroll
            for (int dx = 0; dx < 5; ++dx) {
                a0 = fmaf(row[dx].x, wgt[dy * 5 + dx][0], a0);
                a1 = fmaf(row[dx].y, wgt[dy * 5 + dx][1], a1);
            }
        }
        size_t oidx = base + ((size_t)(y * HW + xpos) << 9);
        ushort2 au = *(const ushort2*)(ATTbf + oidx);
        ushort2 gu = *(const ushort2*)(Gbf + oidx);
        ushort2 o;
        o.x = f2bf((bf2f(au.x) + a0) * bf2f(gu.x));
        o.y = f2bf((bf2f(au.y) + a1) * bf2f(gu.y));
        *(ushort2*)(PRE + oidx) = o;
    }
}

extern "C" void kernel_launch(void* const* d_in, const int* in_sizes, int n_in,
                              void* d_out, int out_size, void* d_ws, size_t ws_size,
                              hipStream_t stream) {
    const float* x      = (const float*)d_in[0];
    const float* qg_w   = (const float*)d_in[1];
    const float* kv_w   = (const float*)d_in[2];
    const float* proj_w = (const float*)d_in[3];
    const float* proj_b = (const float*)d_in[4];
    const float* dwc_w  = (const float*)d_in[5];
    const float* dwc_b  = (const float*)d_in[6];
    const float* power_p= (const float*)d_in[7];
    const float* scale_p= (const float*)d_in[8];
    const float* enh_w  = (const float*)d_in[9];
    const float* bn_g   = (const float*)d_in[10];
    const float* bn_b   = (const float*)d_in[11];
    const float* ew_p   = (const float*)d_in[12];
    const float* pos    = (const float*)d_in[13];

    const size_t NELEM = (size_t)MTOT * CDIM;   // 12,845,056
    float* ws    = (float*)d_ws;
    // layout (float offsets):
    // [0, N)       Q fp32
    // [N, 1.5N)    Gbf ushort
    // [1.5N,1.79N) PKV_A float[7*532480]
    // [2N, 3N)     KFbf ushort[MTOT*1024]; later PREbf in [2N,2.5N)
    // [3N, 3.5N)   Vbf ushort
    // [3.5N, 4N)   ATTbf ushort
    // [4N, 4.5N)   Xbf ushort, then QEbf ushort
    // [4.5N,4.79N) PKV_B float[7*532480]
    // [5N, ...)    SMALL
    float*  Qf   = ws;
    ushort* Gbf  = (ushort*)(ws + NELEM);
    float*  PKV_A= ws + NELEM + NELEM / 2;
    ushort* KFbf = (ushort*)(ws + 2 * NELEM);
    ushort* PREbf= (ushort*)(ws + 2 * NELEM);
    ushort* Vbf  = (ushort*)(ws + 3 * NELEM);
    ushort* ATTbf= (ushort*)(ws + 3 * NELEM + NELEM / 2);
    ushort* Xbf  = (ushort*)(ws + 4 * NELEM);
    ushort* QEbf = (ushort*)(ws + 4 * NELEM);
    float*  PKV_B= ws + 4 * NELEM + NELEM / 2;
    float* SMALL = ws + 5 * NELEM;
    float* ssum  = SMALL;               // 512
    float* ssq   = SMALL + 512;         // 512
    ushort* kvTbf= (ushort*)(SMALL + 9216);      // 655,360 ushorts
    float* invs  = SMALL + 533504;
    float* powr  = SMALL + 534016;
    float* achan = SMALL + 534528;
    float* bchan = SMALL + 535040;
    ushort* Wqg  = (ushort*)(SMALL + 535552);
    ushort* Wkv  = (ushort*)(SMALL + 797696);
    ushort* Wproj= (ushort*)(SMALL + 1059840);

    hipMemsetAsync(SMALL, 0, (size_t)1024 * sizeof(float), stream);

    prep_kernel<<<1, 512, 0, stream>>>(scale_p, power_p, invs, powr);

    cvt_bf16_kernel<<<12544, 256, 0, stream>>>(x, Xbf, 3211264);
    cvt_weights_kernel<<<1280, 256, 0, stream>>>(qg_w, kv_w, proj_w, Wqg, Wkv, Wproj);

    mgemm_qgkv<<<3136, 256, 0, stream>>>(Xbf, Wqg, Wkv, Qf, Gbf, KFbf, Vbf, pos, invs, powr);

    dim3 cgrid(56, 32);
    conv3s_kernel<<<cgrid, 256, 0, stream>>>(Qf, enh_w, QEbf, ssum, ssq);
    bnprep_kernel<<<1, 512, 0, stream>>>(ssum, ssq, bn_g, bn_b, achan, bchan);

    kvred4_kernel<<<dim3(64, 14), 256, 0, stream>>>(KFbf, Vbf, PKV_A, PKV_B);
    kvreduce2_kernel<<<2560, 256, 0, stream>>>(PKV_A, PKV_B, kvTbf);

    attn_mfma_kernel<<<dim3(64, 49), 256, 0, stream>>>(Qf, QEbf, kvTbf, powr,
                                                       achan, bchan, invs, ew_p, ATTbf);

    voutg2_kernel<<<cgrid, 256, 0, stream>>>(Vbf, ATTbf, Gbf, dwc_w, dwc_b, PREbf);

    mgemm_proj<<<784, 256, 0, stream>>>(PREbf, Wproj, (float*)d_out, proj_b);
}

// Round 16
// 475.392 us; speedup vs baseline: 1.1382x; 1.0136x over previous
//
#include <hip/hip_runtime.h>
#include <hip/hip_bf16.h>
#include <math.h>

#define CDIM 512
#define NTOK 3136
#define BATCH 8
#define MTOT (BATCH*NTOK)   // 25088
#define NHEAD 8
#define DHEAD 64
#define HW 56

typedef __attribute__((ext_vector_type(8))) short short8;
typedef __attribute__((ext_vector_type(4))) float f32x4;

__device__ __forceinline__ ushort f2bf(float f) {
    union { float f; unsigned int u; } v; v.f = f;
    unsigned int u = v.u + 0x7FFFu + ((v.u >> 16) & 1u);
    return (ushort)(u >> 16);
}
__device__ __forceinline__ float bf2f(ushort u) {
    union { unsigned int u; float f; } v; v.u = ((unsigned int)u) << 16;
    return v.f;
}

__device__ __forceinline__ void gload_lds16(const void* g, void* lds) {
    __builtin_amdgcn_global_load_lds((const __attribute__((address_space(1))) void*)g,
                                     (__attribute__((address_space(3))) void*)lds,
                                     16, 0, 0);
}

// ---------------- prep ----------------
__global__ void prep_kernel(const float* __restrict__ scale_p,
                            const float* __restrict__ power_p,
                            float* __restrict__ inv_scale,
                            float* __restrict__ power) {
    int c = threadIdx.x;
    if (c < CDIM) {
        float s = log1pf(expf(scale_p[c]));
        inv_scale[c] = 1.0f / s;
        power[c] = 1.0f + 4.0f / (1.0f + expf(-power_p[c]));
    }
}

__global__ __launch_bounds__(256) void cvt_bf16_kernel(const float* __restrict__ src,
                                                       ushort* __restrict__ dst, int n4) {
    int i = blockIdx.x * 256 + threadIdx.x;
    if (i < n4) {
        float4 f = ((const float4*)src)[i];
        ushort4 o;
        o.x = f2bf(f.x); o.y = f2bf(f.y); o.z = f2bf(f.z); o.w = f2bf(f.w);
        ((ushort4*)dst)[i] = o;
    }
}

__global__ __launch_bounds__(256) void cvt_weights_kernel(const float* __restrict__ qg_w,
                                                          const float* __restrict__ kv_w,
                                                          const float* __restrict__ proj_w,
                                                          ushort* __restrict__ Wqg,
                                                          ushort* __restrict__ Wkv,
                                                          ushort* __restrict__ Wproj) {
    int i = blockIdx.x * 256 + threadIdx.x;
    const float* src; ushort* dst; int idx;
    if (i < 131072)      { src = qg_w;   dst = Wqg;   idx = i; }
    else if (i < 262144) { src = kv_w;   dst = Wkv;   idx = i - 131072; }
    else                 { src = proj_w; dst = Wproj; idx = i - 262144; }
    float4 f = ((const float4*)src)[idx];
    ushort4 o;
    o.x = f2bf(f.x); o.y = f2bf(f.y); o.z = f2bf(f.z); o.w = f2bf(f.w);
    ((ushort4*)dst)[idx] = o;
}

// ---------------- merged qg+kv GEMM: BK=32 x 3-buffer counted-vmcnt pipeline (48KB),
// 3 blocks/CU. Fragment swizzle phys = s ^ ((row>>1)&3): 2-way banks (free).
// grid 3136; idp=(bid&7)*392+(bid>>3); mb=idp>>4, ob=idp&15.
// colg=ob*128: [0,512) Qbf | [512,1024) Gbf | [1024,1536) K->KF | [1536,2048) V.
__global__ __launch_bounds__(256, 3) void mgemm_qgkv(const ushort* __restrict__ A,
                                                     const ushort* __restrict__ Wqg,
                                                     const ushort* __restrict__ Wkv,
                                                     ushort* __restrict__ Qout,
                                                     ushort* __restrict__ Gout,
                                                     ushort* __restrict__ KFout,
                                                     ushort* __restrict__ Vout,
                                                     const float* __restrict__ pos,
                                                     const float* __restrict__ invs,
                                                     const float* __restrict__ powr) {
    __shared__ __align__(16) char smem[49152];
    ushort* At = (ushort*)smem;               // [3][128*32] = 24KB
    ushort* Bt = (ushort*)(smem + 24576);     // [3][128*32] = 24KB
    float*  Osh = (float*)smem;               // epilogue alias [64][128] = 32KB

    const int t = threadIdx.x;
    const int w = t >> 6, l = t & 63;
    const int wr = w >> 1, wc = w & 1;

    const int bid = blockIdx.x;
    const int idp = (bid & 7) * 392 + (bid >> 3);
    const int mb = idp >> 4, ob = idp & 15;
    const int m0 = mb * 128;
    const ushort* Bp = (ob < 8) ? (Wqg + (size_t)ob * 128 * CDIM)
                                : (Wkv + (size_t)(ob - 8) * 128 * CDIM);

    // 4 loads/thread per stage (2 A-chunks + 2 B-chunks)
    auto stage = [&](int buf, int ks) {
        const int k0 = ks * 32;
        #pragma unroll
        for (int i = 0; i < 2; ++i) {
            int f = t + i * 256;               // 0..511
            int row = f >> 2, ps = f & 3;
            int ls = ps ^ ((row >> 1) & 3);    // bank-audited involution
            gload_lds16(A + (size_t)(m0 + row) * CDIM + k0 + ls * 8, At + buf * 4096 + f * 8);
            gload_lds16(Bp + (size_t)row * CDIM + k0 + ls * 8, Bt + buf * 4096 + f * 8);
        }
    };

    f32x4 acc[4][4] = {};
    stage(0, 0);
    stage(1, 1);
    const int sl4 = l >> 4;
    for (int ks = 0; ks < 16; ++ks) {
        if (ks < 15) asm volatile("s_waitcnt vmcnt(4)" ::: "memory");
        else         asm volatile("s_waitcnt vmcnt(0)" ::: "memory");
        __builtin_amdgcn_s_barrier();
        if (ks + 2 < 16) stage((ks + 2) % 3, ks + 2);
        const int cur = ks % 3;
        short8 af[4], bfr[4];
        #pragma unroll
        for (int i = 0; i < 4; ++i) {
            int row = wr * 64 + i * 16 + (l & 15);
            int ph = sl4 ^ ((row >> 1) & 3);
            af[i] = *(const short8*)&At[cur * 4096 + row * 32 + ph * 8];
            int rowb = wc * 64 + i * 16 + (l & 15);
            int phb = sl4 ^ ((rowb >> 1) & 3);
            bfr[i] = *(const short8*)&Bt[cur * 4096 + rowb * 32 + phb * 8];
        }
        #pragma unroll
        for (int i = 0; i < 4; ++i)
            #pragma unroll
            for (int j = 0; j < 4; ++j)
                acc[i][j] = __builtin_amdgcn_mfma_f32_16x16x32_bf16(af[i], bfr[j], acc[i][j], 0, 0, 0);
    }
    __syncthreads();   // drain before LDS reuse as Osh

    const int colbase = ob * 128;
    #pragma unroll
    for (int p = 0; p < 2; ++p) {
        if (wr == p) {
            #pragma unroll
            for (int i = 0; i < 4; ++i)
                #pragma unroll
                for (int j = 0; j < 4; ++j)
                    #pragma unroll
                    for (int rr = 0; rr < 4; ++rr) {
                        int row = i * 16 + (l >> 4) * 4 + rr;     // 0..63 in pass
                        int col = wc * 64 + j * 16 + (l & 15);
                        int pc = col ^ (((row >> 2) & 1) << 4);
                        Osh[row * 128 + pc] = acc[i][j][rr];
                    }
        }
        __syncthreads();
        #pragma unroll
        for (int q = 0; q < 8; ++q) {
            int fi = q * 256 + t;
            int rl = fi >> 5, c4 = (fi & 31) * 4;
            int pc4 = c4 ^ (((rl >> 2) & 1) << 4);
            float4 v = *(float4*)&Osh[rl * 128 + pc4];
            int m = m0 + p * 64 + rl;
            if (colbase < 512) {
                ushort4 o;
                o.x = f2bf(v.x); o.y = f2bf(v.y); o.z = f2bf(v.z); o.w = f2bf(v.w);
                *(ushort4*)&Qout[(size_t)m * CDIM + colbase + c4] = o;
            } else if (colbase < 1024) {
                ushort4 o;
                o.x = f2bf(v.x); o.y = f2bf(v.y); o.z = f2bf(v.z); o.w = f2bf(v.w);
                *(ushort4*)&Gout[(size_t)m * CDIM + colbase - 512 + c4] = o;
            } else if (colbase < 1536) {
                int n = m % NTOK;
                int oc = colbase - 1024 + c4;
                float4 pv = *(const float4*)&pos[(size_t)n * CDIM + oc];
                float4 iv = *(const float4*)&invs[oc];
                float4 pw = *(const float4*)&powr[oc];
                float kx0 = (v.x + pv.x) * iv.x, kx1 = (v.y + pv.y) * iv.y;
                float kx2 = (v.z + pv.z) * iv.z, kx3 = (v.w + pv.w) * iv.w;
                float t0 = __powf(fabsf(kx0), pw.x), t1 = __powf(fabsf(kx1), pw.y);
                float t2 = __powf(fabsf(kx2), pw.z), t3 = __powf(fabsf(kx3), pw.w);
                ushort4 up, un;
                up.x = kx0 > 0.f ? f2bf(t0) : 0; un.x = kx0 < 0.f ? f2bf(t0) : 0;
                up.y = kx1 > 0.f ? f2bf(t1) : 0; un.y = kx1 < 0.f ? f2bf(t1) : 0;
                up.z = kx2 > 0.f ? f2bf(t2) : 0; un.z = kx2 < 0.f ? f2bf(t2) : 0;
                up.w = kx3 > 0.f ? f2bf(t3) : 0; un.w = kx3 < 0.f ? f2bf(t3) : 0;
                ushort* dst = KFout + (size_t)m * 1024 + ((oc >> 6) << 7) + (oc & 63);
                *(ushort4*)dst = up;
                *(ushort4*)(dst + 64) = un;
            } else {
                ushort4 o;
                o.x = f2bf(v.x); o.y = f2bf(v.y); o.z = f2bf(v.z); o.w = f2bf(v.w);
                *(ushort4*)&Vout[(size_t)m * CDIM + colbase - 1536 + c4] = o;
            }
        }
        __syncthreads();
    }
}

// ---------------- proj GEMM: dbuf BK=64 (R12 proven), XOR fp32 epilogue ----------------
__global__ __launch_bounds__(256) void mgemm_proj(const ushort* __restrict__ A,
                                                  const ushort* __restrict__ W,
                                                  float* __restrict__ out,
                                                  const float* __restrict__ pb) {
    __shared__ __align__(16) char smem[65536];
    ushort* At = (ushort*)smem;
    ushort* Bt = (ushort*)(smem + 32768);
    float*  Osh = (float*)smem;

    const int t = threadIdx.x;
    const int w = t >> 6, l = t & 63;
    const int wr = w >> 1, wc = w & 1;
    const int r8 = l >> 3, sl = l & 7;
    const int ss = sl ^ r8;

    const int bid = blockIdx.x;
    const int idp = (bid & 7) * 98 + (bid >> 3);
    const int mb = idp >> 2, ob = idp & 3;
    const int m0 = mb * 128;
    const ushort* Bp = W + (size_t)ob * 128 * CDIM;

    auto stage = [&](int buf, int ks) {
        const int k0 = ks * 64;
        #pragma unroll
        for (int c = 0; c < 4; ++c) {
            int rc = (w * 4 + c) * 8 + r8;
            gload_lds16(A + (size_t)(m0 + rc) * CDIM + k0 + ss * 8, At + buf * 8192 + (w * 4 + c) * 512);
            gload_lds16(Bp + (size_t)rc * CDIM + k0 + ss * 8, Bt + buf * 8192 + (w * 4 + c) * 512);
        }
    };

    f32x4 acc[4][4] = {};
    stage(0, 0);
    __syncthreads();
    for (int ks = 0; ks < 8; ++ks) {
        int cur = ks & 1;
        if (ks < 7) stage(cur ^ 1, ks + 1);
        #pragma unroll
        for (int kk = 0; kk < 2; ++kk) {
            short8 af[4], bfr[4];
            const int sbase = kk * 4 + (l >> 4);
            #pragma unroll
            for (int i = 0; i < 4; ++i) {
                int row = wr * 64 + i * 16 + (l & 15);
                af[i] = *(const short8*)&At[cur * 8192 + row * 64 + ((sbase ^ (row & 7)) * 8)];
                int rowb = wc * 64 + i * 16 + (l & 15);
                bfr[i] = *(const short8*)&Bt[cur * 8192 + rowb * 64 + ((sbase ^ (rowb & 7)) * 8)];
            }
            #pragma unroll
            for (int i = 0; i < 4; ++i)
                #pragma unroll
                for (int j = 0; j < 4; ++j)
                    acc[i][j] = __builtin_amdgcn_mfma_f32_16x16x32_bf16(af[i], bfr[j], acc[i][j], 0, 0, 0);
        }
        __syncthreads();
    }

    #pragma unroll
    for (int i = 0; i < 4; ++i)
        #pragma unroll
        for (int j = 0; j < 4; ++j)
            #pragma unroll
            for (int rr = 0; rr < 4; ++rr) {
                int row = wr * 64 + i * 16 + (l >> 4) * 4 + rr;
                int col = wc * 64 + j * 16 + (l & 15);
                int pc = col ^ (((row >> 2) & 1) << 4);
                Osh[row * 128 + pc] = acc[i][j][rr];
            }
    __syncthreads();

    const int colbase = ob * 128;
    #pragma unroll
    for (int q = 0; q < 16; ++q) {
        int fi = q * 256 + t;
        int r = fi >> 5, c4 = (fi & 31) * 4;
        int pc4 = c4 ^ (((r >> 2) & 1) << 4);
        float4 v = *(float4*)&Osh[r * 128 + pc4];
        float4 b4 = *(const float4*)&pb[colbase + c4];
        v.x += b4.x; v.y += b4.y; v.z += b4.z; v.w += b4.w;
        *(float4*)&out[(size_t)(m0 + r) * CDIM + colbase + c4] = v;
    }
}

// ---------------- fused 3x3 depthwise conv (bf16 in/out) + BN stats ----------------
__global__ __launch_bounds__(256) void conv3s_kernel(const ushort* __restrict__ Qbf,
                                                     const float* __restrict__ enh_w,
                                                     ushort* __restrict__ QEbf,
                                                     float* __restrict__ ssum,
                                                     float* __restrict__ ssq) {
    const int t = threadIdx.x;
    const int c0 = t * 2;
    const int xpos = blockIdx.x;
    const int byc = blockIdx.y;
    const int b = byc >> 2, yc = byc & 3;
    const int y0 = yc * 14;

    float wgt[9][2];
    #pragma unroll
    for (int tap = 0; tap < 9; ++tap) {
        wgt[tap][0] = enh_w[c0 * 9 + tap];
        wgt[tap][1] = enh_w[(c0 + 1) * 9 + tap];
    }
    const size_t base = (size_t)b * NTOK * CDIM + c0;

    float2 win[3][3];
    auto ldrow = [&](int yy, float2* dst) {
        #pragma unroll
        for (int dx = 0; dx < 3; ++dx) {
            int xx = xpos + dx - 1;
            bool ok = (yy >= 0 && yy < HW && xx >= 0 && xx < HW);
            if (ok) {
                ushort2 uv = *(const ushort2*)(Qbf + base + ((size_t)(yy * HW + xx) << 9));
                dst[dx] = make_float2(bf2f(uv.x), bf2f(uv.y));
            } else {
                dst[dx] = make_float2(0.f, 0.f);
            }
        }
    };
    ldrow(y0 - 1, win[0]);
    ldrow(y0,     win[1]);

    float s1a = 0.f, s2a = 0.f, s1b = 0.f, s2b = 0.f;
    #pragma unroll
    for (int i = 0; i < 14; ++i) {
        int y = y0 + i;
        ldrow(y + 1, win[(i + 2) % 3]);
        float a0 = 0.f, a1 = 0.f;
        #pragma unroll
        for (int dy = 0; dy < 3; ++dy) {
            float2* row = win[(i + dy) % 3];
            #pragma unroll
            for (int dx = 0; dx < 3; ++dx) {
                a0 = fmaf(row[dx].x, wgt[dy * 3 + dx][0], a0);
                a1 = fmaf(row[dx].y, wgt[dy * 3 + dx][1], a1);
            }
        }
        ushort2 o; o.x = f2bf(a0); o.y = f2bf(a1);
        *(ushort2*)(QEbf + base + ((size_t)(y * HW + xpos) << 9)) = o;
        s1a += a0; s2a += a0 * a0;
        s1b += a1; s2b += a1 * a1;
    }
    atomicAdd(&ssum[c0], s1a);     atomicAdd(&ssq[c0], s2a);
    atomicAdd(&ssum[c0 + 1], s1b); atomicAdd(&ssq[c0 + 1], s2b);
}

__global__ void bnprep_kernel(const float* __restrict__ ssum, const float* __restrict__ ssq,
                              const float* __restrict__ bn_g, const float* __restrict__ bn_b,
                              float* __restrict__ achan, float* __restrict__ bchan) {
    int c = threadIdx.x;
    if (c < CDIM) {
        const float invM = 1.0f / (float)MTOT;
        float mean = ssum[c] * invM;
        float var  = ssq[c] * invM - mean * mean;
        float a = bn_g[c] * rsqrtf(var + 1e-5f);
        achan[c] = a;
        bchan[c] = bn_b[c] - mean * a;
    }
}

// ---------------- kvred v4: zero-LDS register MFMA GEMM, 14 chunks, split PKV --------
__global__ __launch_bounds__(256) void kvred4_kernel(const ushort* __restrict__ KF,
                                                     const ushort* __restrict__ Vbf,
                                                     float* __restrict__ PKV_A,
                                                     float* __restrict__ PKV_B) {
    const int bh = blockIdx.x, chunk = blockIdx.y;   // chunk 0..13
    const int b = bh >> 3, head = bh & 7;
    const int t = threadIdx.x;
    const int w = t >> 6, l = t & 63;
    const int lr = l & 15;
    const int ns = (l >> 4) * 8;

    const int nbase = b * NTOK + chunk * 224;
    const ushort* kf0 = KF  + ((size_t)(nbase + ns)) * 1024 + head * 128 + (w * 32 + lr);
    const ushort* vb0 = Vbf + ((size_t)(nbase + ns)) * 512  + head * 64  + lr;

    short8 ones;
    #pragma unroll
    for (int j = 0; j < 8; ++j) ones[j] = (lr == 0) ? (short)0x3F80 : (short)0;

    f32x4 acc[2][5] = {};
    for (int tile = 0; tile < 7; ++tile) {
        union { uint u[4]; short8 s; } ua[2], ub[4];
        #pragma unroll
        for (int i = 0; i < 2; ++i) {
            #pragma unroll
            for (int j = 0; j < 4; ++j) {
                uint lo = kf0[i * 16 + (size_t)(2 * j) * 1024];
                uint hi = kf0[i * 16 + (size_t)(2 * j + 1) * 1024];
                ua[i].u[j] = lo | (hi << 16);
            }
        }
        #pragma unroll
        for (int j5 = 0; j5 < 4; ++j5) {
            #pragma unroll
            for (int j = 0; j < 4; ++j) {
                uint lo = vb0[j5 * 16 + (size_t)(2 * j) * 512];
                uint hi = vb0[j5 * 16 + (size_t)(2 * j + 1) * 512];
                ub[j5].u[j] = lo | (hi << 16);
            }
        }
        #pragma unroll
        for (int i = 0; i < 2; ++i) {
            #pragma unroll
            for (int j5 = 0; j5 < 4; ++j5)
                acc[i][j5] = __builtin_amdgcn_mfma_f32_16x16x32_bf16(ua[i].s, ub[j5].s, acc[i][j5], 0, 0, 0);
            acc[i][4] = __builtin_amdgcn_mfma_f32_16x16x32_bf16(ua[i].s, ones, acc[i][4], 0, 0, 0);
        }
        kf0 += (size_t)32 * 1024;
        vb0 += (size_t)32 * 512;
    }
    float* dstb = (chunk < 7)
        ? (PKV_A + ((size_t)(chunk * 64 + bh)) * 8320)
        : (PKV_B + ((size_t)((chunk - 7) * 64 + bh)) * 8320);
    #pragma unroll
    for (int i = 0; i < 2; ++i) {
        int d0 = w * 32 + i * 16 + (l >> 4) * 4;
        #pragma unroll
        for (int j = 0; j < 5; ++j) {
            int e = j * 16 + lr;
            if (j < 4 || e == 64)
                *(f32x4*)(dstb + (size_t)e * 128 + d0) = acc[i][j];
        }
    }
}

// ---------------- reduce split partials -> pre-swizzled bf16 BT image [bh][80][128] -----
__global__ __launch_bounds__(256) void kvreduce2_kernel(const float* __restrict__ PKV_A,
                                                        const float* __restrict__ PKV_B,
                                                        ushort* __restrict__ kvTbf) {
    int gid = blockIdx.x * 256 + threadIdx.x;   // 64*80*128 = 655360
    const float inv_n = 1.0f / (float)NTOK;
    int bh = gid / 10240;
    int r  = gid - bh * 10240;
    int row = r >> 7, dcol = r & 127;
    int dlog = (((dcol >> 3) ^ (row & 7)) << 3) | (dcol & 7);
    float s = 0.f;
    if (row < 66) {
        int rsel, dsel;
        if (row < 64) { rsel = row; dsel = (row >= 32) ? (dlog ^ 64) : dlog; }
        else          { rsel = 64;  dsel = (row == 65) ? (dlog ^ 64) : dlog; }
        size_t idx = (size_t)bh * 8320 + rsel * 128 + dsel;
        #pragma unroll
        for (int c = 0; c < 7; ++c) s += PKV_A[(size_t)c * 532480 + idx];
        #pragma unroll
        for (int c = 0; c < 7; ++c) s += PKV_B[(size_t)c * 532480 + idx];
    }
    kvTbf[gid] = (row < 66) ? f2bf(s * inv_n) : (ushort)0;
}

// ---------------- attention apply via MFMA (qfin fused), bf16 Q/QE in, bf16 out -------
__global__ __launch_bounds__(256) void attn_mfma_kernel(const ushort* __restrict__ Qbf,
                                                        const ushort* __restrict__ QEbf,
                                                        const ushort* __restrict__ kvTbf,
                                                        const float* __restrict__ power,
                                                        const float* __restrict__ achan,
                                                        const float* __restrict__ bchan,
                                                        const float* __restrict__ invs,
                                                        const float* __restrict__ ewp,
                                                        ushort* __restrict__ ATTbf) {
    __shared__ ushort QF[64 * 128];
    __shared__ ushort BT[80 * 128];
    const int bh = blockIdx.x, tb = blockIdx.y;
    const int b = bh >> 3, head = bh & 7;
    const int t = threadIdx.x;
    const int w = t >> 6, l = t & 63;

    #pragma unroll
    for (int i = 0; i < 5; ++i) {
        int f = i * 256 + t;
        gload_lds16(kvTbf + (size_t)bh * 10240 + f * 8, BT + f * 8);
    }

    const int c = l, hc = head * 64 + c;
    const float p = power[hc];
    const float ac = achan[hc], bc = bchan[hc], iv = invs[hc], ew = ewp[0];
    #pragma unroll
    for (int i = 0; i < 16; ++i) {
        int tok = i * 4 + w;
        size_t off = ((size_t)(b * NTOK + tb * 64 + tok)) * CDIM + hc;
        float q = bf2f(Qbf[off]);
        float qe = bf2f(QEbf[off]);
        q = (q + ew * fmaxf(fmaf(ac, qe, bc), 0.f)) * iv;
        float ax = fabsf(q);
        float tp = ax > 0.f ? __powf(ax, p) : 0.f;
        float qp = q > 0.f ? tp : 0.f;
        float qn = q < 0.f ? tp : 0.f;
        int sw = tok & 7;
        QF[tok * 128 + (((c >> 3) ^ sw) * 8) + (c & 7)]       = f2bf(qp);
        QF[tok * 128 + ((((c >> 3) + 8) ^ sw) * 8) + (c & 7)] = f2bf(qn);
    }
    __syncthreads();

    f32x4 acc[5] = {};
    #pragma unroll
    for (int kk = 0; kk < 4; ++kk) {
        int sbase = kk * 4 + (l >> 4);
        int rowa = w * 16 + (l & 15);
        short8 af = *(const short8*)&QF[rowa * 128 + ((sbase ^ (rowa & 7)) * 8)];
        #pragma unroll
        for (int j = 0; j < 5; ++j) {
            int rowb = j * 16 + (l & 15);
            short8 bf = *(const short8*)&BT[rowb * 128 + ((sbase ^ (rowb & 7)) * 8)];
            acc[j] = __builtin_amdgcn_mfma_f32_16x16x32_bf16(af, bf, acc[j], 0, 0, 0);
        }
    }
    __syncthreads();

    ushort* Oout = QF;
    #pragma unroll
    for (int rr = 0; rr < 4; ++rr) {
        float ssim = __shfl(acc[4][rr], (l & 48));
        float sopp = __shfl(acc[4][rr], (l & 48) + 1);
        float zs = 1.f / (ssim + 1e-6f);
        float zo = 1.f / (sopp + 1e-6f);
        int tokl = w * 16 + (l >> 4) * 4 + rr;
        #pragma unroll
        for (int j = 0; j < 4; ++j) {
            int e = j * 16 + (l & 15);
            Oout[tokl * 64 + e] = f2bf(acc[j][rr] * (j < 2 ? zs : zo));
        }
    }
    __syncthreads();

    #pragma unroll
    for (int i = 0; i < 2; ++i) {
        int idx = i * 256 + t;
        int tokl = idx >> 3, ch = (idx & 7) * 8;
        short8 vv = *(short8*)&Oout[tokl * 64 + ch];
        *(short8*)&ATTbf[((size_t)(b * NTOK + tb * 64 + tokl)) * CDIM + head * 64 + ch] = vv;
    }
}

// ---------------- v 5x5 depthwise conv (bf16 V) + gate (bf16 ATT, bf16 G) --------------
__global__ __launch_bounds__(256) void voutg2_kernel(const ushort* __restrict__ Vbf,
                                                     const ushort* __restrict__ ATTbf,
                                                     const ushort* __restrict__ Gbf,
                                                     const float* __restrict__ dwc_w,
                                                     const float* __restrict__ dwc_b,
                                                     ushort* __restrict__ PRE) {
    const int t = threadIdx.x;
    const int c0 = t * 2;
    const int xpos = blockIdx.x;
    const int byc = blockIdx.y;
    const int b = byc >> 2, yc = byc & 3;
    const int y0 = yc * 14;
    const int dch = c0 & 63;

    float wgt[25][2];
    #pragma unroll
    for (int tap = 0; tap < 25; ++tap) {
        wgt[tap][0] = dwc_w[dch * 25 + tap];
        wgt[tap][1] = dwc_w[(dch + 1) * 25 + tap];
    }
    const float bias0 = dwc_b[dch], bias1 = dwc_b[dch + 1];
    const size_t base = (size_t)b * NTOK * CDIM + c0;

    float2 win[5][5];
    auto ldrow = [&](int yy, float2* dst) {
        #pragma unroll
        for (int dx = 0; dx < 5; ++dx) {
            int xx = xpos + dx - 2;
            bool ok = (yy >= 0 && yy < HW && xx >= 0 && xx < HW);
            if (ok) {
                ushort2 uv = *(const ushort2*)(Vbf + base + ((size_t)(yy * HW + xx) << 9));
                dst[dx] = make_float2(bf2f(uv.x), bf2f(uv.y));
            } else {
                dst[dx] = make_float2(0.f, 0.f);
            }
        }
    };
    ldrow(y0 - 2, win[0]);
    ldrow(y0 - 1, win[1]);
    ldrow(y0,     win[2]);
    ldrow(y0 + 1, win[3]);

    #pragma unroll
    for (int i = 0; i < 14; ++i) {
        int y = y0 + i;
        ldrow(y + 2, win[(i + 4) % 5]);
        float a0 = bias0, a1 = bias1;
        #pragma unroll
        for (int dy = 0; dy < 5; ++dy) {
            float2* row = win[(i + dy) % 5];
            #pragma unroll
            for (int dx = 0; dx < 5; ++dx) {
                a0 = fmaf(row[dx].x, wgt[dy * 5 + dx][0], a0);
                a1 = fmaf(row[dx].y, wgt[dy * 5 + dx][1], a1);
            }
        }
        size_t oidx = base + ((size_t)(y * HW + xpos) << 9);
        ushort2 au = *(const ushort2*)(ATTbf + oidx);
        ushort2 gu = *(const ushort2*)(Gbf + oidx);
        ushort2 o;
        o.x = f2bf((bf2f(au.x) + a0) * bf2f(gu.x));
        o.y = f2bf((bf2f(au.y) + a1) * bf2f(gu.y));
        *(ushort2*)(PRE + oidx) = o;
    }
}

extern "C" void kernel_launch(void* const* d_in, const int* in_sizes, int n_in,
                              void* d_out, int out_size, void* d_ws, size_t ws_size,
                              hipStream_t stream) {
    const float* x      = (const float*)d_in[0];
    const float* qg_w   = (const float*)d_in[1];
    const float* kv_w   = (const float*)d_in[2];
    const float* proj_w = (const float*)d_in[3];
    const float* proj_b = (const float*)d_in[4];
    const float* dwc_w  = (const float*)d_in[5];
    const float* dwc_b  = (const float*)d_in[6];
    const float* power_p= (const float*)d_in[7];
    const float* scale_p= (const float*)d_in[8];
    const float* enh_w  = (const float*)d_in[9];
    const float* bn_g   = (const float*)d_in[10];
    const float* bn_b   = (const float*)d_in[11];
    const float* ew_p   = (const float*)d_in[12];
    const float* pos    = (const float*)d_in[13];

    const size_t NELEM = (size_t)MTOT * CDIM;   // 12,845,056
    float* ws    = (float*)d_ws;
    // layout (float offsets):
    // [0, 0.5N)    Qbf ushort
    // [N, 1.5N)    Gbf ushort
    // [1.5N,1.79N) PKV_A float[7*532480]
    // [2N, 3N)     KFbf ushort[MTOT*1024]; later PREbf in [2N,2.5N)
    // [3N, 3.5N)   Vbf ushort
    // [3.5N, 4N)   ATTbf ushort
    // [4N, 4.5N)   Xbf ushort, then QEbf ushort
    // [4.5N,4.79N) PKV_B float[7*532480]
    // [5N, ...)    SMALL
    ushort* Qbf  = (ushort*)ws;
    ushort* Gbf  = (ushort*)(ws + NELEM);
    float*  PKV_A= ws + NELEM + NELEM / 2;
    ushort* KFbf = (ushort*)(ws + 2 * NELEM);
    ushort* PREbf= (ushort*)(ws + 2 * NELEM);
    ushort* Vbf  = (ushort*)(ws + 3 * NELEM);
    ushort* ATTbf= (ushort*)(ws + 3 * NELEM + NELEM / 2);
    ushort* Xbf  = (ushort*)(ws + 4 * NELEM);
    ushort* QEbf = (ushort*)(ws + 4 * NELEM);
    float*  PKV_B= ws + 4 * NELEM + NELEM / 2;
    float* SMALL = ws + 5 * NELEM;
    float* ssum  = SMALL;               // 512
    float* ssq   = SMALL + 512;         // 512
    ushort* kvTbf= (ushort*)(SMALL + 9216);      // 655,360 ushorts
    float* invs  = SMALL + 533504;
    float* powr  = SMALL + 534016;
    float* achan = SMALL + 534528;
    float* bchan = SMALL + 535040;
    ushort* Wqg  = (ushort*)(SMALL + 535552);
    ushort* Wkv  = (ushort*)(SMALL + 797696);
    ushort* Wproj= (ushort*)(SMALL + 1059840);

    hipMemsetAsync(SMALL, 0, (size_t)1024 * sizeof(float), stream);

    prep_kernel<<<1, 512, 0, stream>>>(scale_p, power_p, invs, powr);

    cvt_bf16_kernel<<<12544, 256, 0, stream>>>(x, Xbf, 3211264);
    cvt_weights_kernel<<<1280, 256, 0, stream>>>(qg_w, kv_w, proj_w, Wqg, Wkv, Wproj);

    mgemm_qgkv<<<3136, 256, 0, stream>>>(Xbf, Wqg, Wkv, Qbf, Gbf, KFbf, Vbf, pos, invs, powr);

    dim3 cgrid(56, 32);
    conv3s_kernel<<<cgrid, 256, 0, stream>>>(Qbf, enh_w, QEbf, ssum, ssq);
    bnprep_kernel<<<1, 512, 0, stream>>>(ssum, ssq, bn_g, bn_b, achan, bchan);

    kvred4_kernel<<<dim3(64, 14), 256, 0, stream>>>(KFbf, Vbf, PKV_A, PKV_B);
    kvreduce2_kernel<<<2560, 256, 0, stream>>>(PKV_A, PKV_B, kvTbf);

    attn_mfma_kernel<<<dim3(64, 49), 256, 0, stream>>>(Qbf, QEbf, kvTbf, powr,
                                                       achan, bchan, invs, ew_p, ATTbf);

    voutg2_kernel<<<cgrid, 256, 0, stream>>>(Vbf, ATTbf, Gbf, dwc_w, dwc_b, PREbf);

    mgemm_proj<<<784, 256, 0, stream>>>(PREbf, Wproj, (float*)d_out, proj_b);
}

// Round 17
// 462.116 us; speedup vs baseline: 1.1709x; 1.0287x over previous
//
#include <hip/hip_runtime.h>
#include <hip/hip_bf16.h>
#include <math.h>

#define CDIM 512
#define NTOK 3136
#define BATCH 8
#define MTOT (BATCH*NTOK)   // 25088
#define NHEAD 8
#define DHEAD 64
#define HW 56

typedef __attribute__((ext_vector_type(8))) short short8;
typedef __attribute__((ext_vector_type(4))) float f32x4;

__device__ __forceinline__ ushort f2bf(float f) {
    union { float f; unsigned int u; } v; v.f = f;
    unsigned int u = v.u + 0x7FFFu + ((v.u >> 16) & 1u);
    return (ushort)(u >> 16);
}
__device__ __forceinline__ float bf2f(ushort u) {
    union { unsigned int u; float f; } v; v.u = ((unsigned int)u) << 16;
    return v.f;
}

__device__ __forceinline__ void gload_lds16(const void* g, void* lds) {
    __builtin_amdgcn_global_load_lds((const __attribute__((address_space(1))) void*)g,
                                     (__attribute__((address_space(3))) void*)lds,
                                     16, 0, 0);
}

__global__ __launch_bounds__(256) void cvt_bf16_kernel(const float* __restrict__ src,
                                                       ushort* __restrict__ dst, int n4) {
    int i = blockIdx.x * 256 + threadIdx.x;
    if (i < n4) {
        float4 f = ((const float4*)src)[i];
        ushort4 o;
        o.x = f2bf(f.x); o.y = f2bf(f.y); o.z = f2bf(f.z); o.w = f2bf(f.w);
        ((ushort4*)dst)[i] = o;
    }
}

// weights cvt + prep fused: blocks 0..1279 weights; 1280/1281 prep channels.
__global__ __launch_bounds__(256) void cvt_weights_kernel(const float* __restrict__ qg_w,
                                                          const float* __restrict__ kv_w,
                                                          const float* __restrict__ proj_w,
                                                          ushort* __restrict__ Wqg,
                                                          ushort* __restrict__ Wkv,
                                                          ushort* __restrict__ Wproj,
                                                          const float* __restrict__ scale_p,
                                                          const float* __restrict__ power_p,
                                                          float* __restrict__ inv_scale,
                                                          float* __restrict__ power) {
    int blk = blockIdx.x;
    if (blk >= 1280) {
        int c = (blk - 1280) * 256 + threadIdx.x;
        float s = log1pf(expf(scale_p[c]));
        inv_scale[c] = 1.0f / s;
        power[c] = 1.0f + 4.0f / (1.0f + expf(-power_p[c]));
        return;
    }
    int i = blk * 256 + threadIdx.x;
    const float* src; ushort* dst; int idx;
    if (i < 131072)      { src = qg_w;   dst = Wqg;   idx = i; }
    else if (i < 262144) { src = kv_w;   dst = Wkv;   idx = i - 131072; }
    else                 { src = proj_w; dst = Wproj; idx = i - 262144; }
    float4 f = ((const float4*)src)[idx];
    ushort4 o;
    o.x = f2bf(f.x); o.y = f2bf(f.y); o.z = f2bf(f.z); o.w = f2bf(f.w);
    ((ushort4*)dst)[idx] = o;
}

// ---------------- merged qg+kv GEMM: BK=32 x 3-buffer counted-vmcnt pipeline (48KB),
// 3 blocks/CU, 16B-store epilogue. grid 3136; idp=(bid&7)*392+(bid>>3); mb=idp>>4, ob=idp&15.
__global__ __launch_bounds__(256, 3) void mgemm_qgkv(const ushort* __restrict__ A,
                                                     const ushort* __restrict__ Wqg,
                                                     const ushort* __restrict__ Wkv,
                                                     ushort* __restrict__ Qout,
                                                     ushort* __restrict__ Gout,
                                                     ushort* __restrict__ KFout,
                                                     ushort* __restrict__ Vout,
                                                     const float* __restrict__ pos,
                                                     const float* __restrict__ invs,
                                                     const float* __restrict__ powr) {
    __shared__ __align__(16) char smem[49152];
    ushort* At = (ushort*)smem;               // [3][128*32]
    ushort* Bt = (ushort*)(smem + 24576);     // [3][128*32]
    float*  Osh = (float*)smem;               // epilogue alias [64][128]

    const int t = threadIdx.x;
    const int w = t >> 6, l = t & 63;
    const int wr = w >> 1, wc = w & 1;

    const int bid = blockIdx.x;
    const int idp = (bid & 7) * 392 + (bid >> 3);
    const int mb = idp >> 4, ob = idp & 15;
    const int m0 = mb * 128;
    const ushort* Bp = (ob < 8) ? (Wqg + (size_t)ob * 128 * CDIM)
                                : (Wkv + (size_t)(ob - 8) * 128 * CDIM);

    auto stage = [&](int buf, int ks) {
        const int k0 = ks * 32;
        #pragma unroll
        for (int i = 0; i < 2; ++i) {
            int f = t + i * 256;
            int row = f >> 2, ps = f & 3;
            int ls = ps ^ ((row >> 1) & 3);
            gload_lds16(A + (size_t)(m0 + row) * CDIM + k0 + ls * 8, At + buf * 4096 + f * 8);
            gload_lds16(Bp + (size_t)row * CDIM + k0 + ls * 8, Bt + buf * 4096 + f * 8);
        }
    };

    f32x4 acc[4][4] = {};
    stage(0, 0);
    stage(1, 1);
    const int sl4 = l >> 4;
    for (int ks = 0; ks < 16; ++ks) {
        if (ks < 15) asm volatile("s_waitcnt vmcnt(4)" ::: "memory");
        else         asm volatile("s_waitcnt vmcnt(0)" ::: "memory");
        __builtin_amdgcn_s_barrier();
        if (ks + 2 < 16) stage((ks + 2) % 3, ks + 2);
        const int cur = ks % 3;
        short8 af[4], bfr[4];
        #pragma unroll
        for (int i = 0; i < 4; ++i) {
            int row = wr * 64 + i * 16 + (l & 15);
            int ph = sl4 ^ ((row >> 1) & 3);
            af[i] = *(const short8*)&At[cur * 4096 + row * 32 + ph * 8];
            int rowb = wc * 64 + i * 16 + (l & 15);
            int phb = sl4 ^ ((rowb >> 1) & 3);
            bfr[i] = *(const short8*)&Bt[cur * 4096 + rowb * 32 + phb * 8];
        }
        #pragma unroll
        for (int i = 0; i < 4; ++i)
            #pragma unroll
            for (int j = 0; j < 4; ++j)
                acc[i][j] = __builtin_amdgcn_mfma_f32_16x16x32_bf16(af[i], bfr[j], acc[i][j], 0, 0, 0);
    }
    __syncthreads();

    const int colbase = ob * 128;
    #pragma unroll
    for (int p = 0; p < 2; ++p) {
        if (wr == p) {
            #pragma unroll
            for (int i = 0; i < 4; ++i)
                #pragma unroll
                for (int j = 0; j < 4; ++j)
                    #pragma unroll
                    for (int rr = 0; rr < 4; ++rr) {
                        int row = i * 16 + (l >> 4) * 4 + rr;
                        int col = wc * 64 + j * 16 + (l & 15);
                        int pc = col ^ (((row >> 2) & 1) << 4);
                        Osh[row * 128 + pc] = acc[i][j][rr];
                    }
        }
        __syncthreads();
        #pragma unroll
        for (int q = 0; q < 4; ++q) {
            int fi = q * 256 + t;              // 0..1023
            int rl = fi >> 4;                  // 0..63
            int c8 = (fi & 15) * 8;            // 0..120
            int xo = ((rl >> 2) & 1) << 4;
            float4 va = *(float4*)&Osh[rl * 128 + (c8 ^ xo)];
            float4 vb = *(float4*)&Osh[rl * 128 + ((c8 + 4) ^ xo)];
            int m = m0 + p * 64 + rl;
            if (colbase < 512) {
                union { ushort u[8]; short8 s; } o;
                o.u[0]=f2bf(va.x); o.u[1]=f2bf(va.y); o.u[2]=f2bf(va.z); o.u[3]=f2bf(va.w);
                o.u[4]=f2bf(vb.x); o.u[5]=f2bf(vb.y); o.u[6]=f2bf(vb.z); o.u[7]=f2bf(vb.w);
                *(short8*)&Qout[(size_t)m * CDIM + colbase + c8] = o.s;
            } else if (colbase < 1024) {
                union { ushort u[8]; short8 s; } o;
                o.u[0]=f2bf(va.x); o.u[1]=f2bf(va.y); o.u[2]=f2bf(va.z); o.u[3]=f2bf(va.w);
                o.u[4]=f2bf(vb.x); o.u[5]=f2bf(vb.y); o.u[6]=f2bf(vb.z); o.u[7]=f2bf(vb.w);
                *(short8*)&Gout[(size_t)m * CDIM + colbase - 512 + c8] = o.s;
            } else if (colbase < 1536) {
                int n = m % NTOK;
                int oc = colbase - 1024 + c8;
                const float* pp = &pos[(size_t)n * CDIM + oc];
                float4 pva = *(const float4*)pp;
                float4 pvb = *(const float4*)(pp + 4);
                float4 iva = *(const float4*)&invs[oc];
                float4 ivb = *(const float4*)&invs[oc + 4];
                float4 pwa = *(const float4*)&powr[oc];
                float4 pwb = *(const float4*)&powr[oc + 4];
                float kx[8], tp[8];
                kx[0]=(va.x+pva.x)*iva.x; kx[1]=(va.y+pva.y)*iva.y;
                kx[2]=(va.z+pva.z)*iva.z; kx[3]=(va.w+pva.w)*iva.w;
                kx[4]=(vb.x+pvb.x)*ivb.x; kx[5]=(vb.y+pvb.y)*ivb.y;
                kx[6]=(vb.z+pvb.z)*ivb.z; kx[7]=(vb.w+pvb.w)*ivb.w;
                tp[0]=__powf(fabsf(kx[0]),pwa.x); tp[1]=__powf(fabsf(kx[1]),pwa.y);
                tp[2]=__powf(fabsf(kx[2]),pwa.z); tp[3]=__powf(fabsf(kx[3]),pwa.w);
                tp[4]=__powf(fabsf(kx[4]),pwb.x); tp[5]=__powf(fabsf(kx[5]),pwb.y);
                tp[6]=__powf(fabsf(kx[6]),pwb.z); tp[7]=__powf(fabsf(kx[7]),pwb.w);
                union { ushort u[8]; short8 s; } up, un;
                #pragma unroll
                for (int e = 0; e < 8; ++e) {
                    ushort b = f2bf(tp[e]);
                    up.u[e] = kx[e] > 0.f ? b : (ushort)0;
                    un.u[e] = kx[e] < 0.f ? b : (ushort)0;
                }
                ushort* dst = KFout + (size_t)m * 1024 + ((oc >> 6) << 7) + (oc & 63);
                *(short8*)dst = up.s;
                *(short8*)(dst + 64) = un.s;
            } else {
                union { ushort u[8]; short8 s; } o;
                o.u[0]=f2bf(va.x); o.u[1]=f2bf(va.y); o.u[2]=f2bf(va.z); o.u[3]=f2bf(va.w);
                o.u[4]=f2bf(vb.x); o.u[5]=f2bf(vb.y); o.u[6]=f2bf(vb.z); o.u[7]=f2bf(vb.w);
                *(short8*)&Vout[(size_t)m * CDIM + colbase - 1536 + c8] = o.s;
            }
        }
        __syncthreads();
    }
}

// ---------------- proj GEMM: dbuf BK=64, XOR fp32 epilogue ----------------
__global__ __launch_bounds__(256) void mgemm_proj(const ushort* __restrict__ A,
                                                  const ushort* __restrict__ W,
                                                  float* __restrict__ out,
                                                  const float* __restrict__ pb) {
    __shared__ __align__(16) char smem[65536];
    ushort* At = (ushort*)smem;
    ushort* Bt = (ushort*)(smem + 32768);
    float*  Osh = (float*)smem;

    const int t = threadIdx.x;
    const int w = t >> 6, l = t & 63;
    const int wr = w >> 1, wc = w & 1;
    const int r8 = l >> 3, sl = l & 7;
    const int ss = sl ^ r8;

    const int bid = blockIdx.x;
    const int idp = (bid & 7) * 98 + (bid >> 3);
    const int mb = idp >> 2, ob = idp & 3;
    const int m0 = mb * 128;
    const ushort* Bp = W + (size_t)ob * 128 * CDIM;

    auto stage = [&](int buf, int ks) {
        const int k0 = ks * 64;
        #pragma unroll
        for (int c = 0; c < 4; ++c) {
            int rc = (w * 4 + c) * 8 + r8;
            gload_lds16(A + (size_t)(m0 + rc) * CDIM + k0 + ss * 8, At + buf * 8192 + (w * 4 + c) * 512);
            gload_lds16(Bp + (size_t)rc * CDIM + k0 + ss * 8, Bt + buf * 8192 + (w * 4 + c) * 512);
        }
    };

    f32x4 acc[4][4] = {};
    stage(0, 0);
    __syncthreads();
    for (int ks = 0; ks < 8; ++ks) {
        int cur = ks & 1;
        if (ks < 7) stage(cur ^ 1, ks + 1);
        #pragma unroll
        for (int kk = 0; kk < 2; ++kk) {
            short8 af[4], bfr[4];
            const int sbase = kk * 4 + (l >> 4);
            #pragma unroll
            for (int i = 0; i < 4; ++i) {
                int row = wr * 64 + i * 16 + (l & 15);
                af[i] = *(const short8*)&At[cur * 8192 + row * 64 + ((sbase ^ (row & 7)) * 8)];
                int rowb = wc * 64 + i * 16 + (l & 15);
                bfr[i] = *(const short8*)&Bt[cur * 8192 + rowb * 64 + ((sbase ^ (rowb & 7)) * 8)];
            }
            #pragma unroll
            for (int i = 0; i < 4; ++i)
                #pragma unroll
                for (int j = 0; j < 4; ++j)
                    acc[i][j] = __builtin_amdgcn_mfma_f32_16x16x32_bf16(af[i], bfr[j], acc[i][j], 0, 0, 0);
        }
        __syncthreads();
    }

    #pragma unroll
    for (int i = 0; i < 4; ++i)
        #pragma unroll
        for (int j = 0; j < 4; ++j)
            #pragma unroll
            for (int rr = 0; rr < 4; ++rr) {
                int row = wr * 64 + i * 16 + (l >> 4) * 4 + rr;
                int col = wc * 64 + j * 16 + (l & 15);
                int pc = col ^ (((row >> 2) & 1) << 4);
                Osh[row * 128 + pc] = acc[i][j][rr];
            }
    __syncthreads();

    const int colbase = ob * 128;
    #pragma unroll
    for (int q = 0; q < 16; ++q) {
        int fi = q * 256 + t;
        int r = fi >> 5, c4 = (fi & 31) * 4;
        int pc4 = c4 ^ (((r >> 2) & 1) << 4);
        float4 v = *(float4*)&Osh[r * 128 + pc4];
        float4 b4 = *(const float4*)&pb[colbase + c4];
        v.x += b4.x; v.y += b4.y; v.z += b4.z; v.w += b4.w;
        *(float4*)&out[(size_t)(m0 + r) * CDIM + colbase + c4] = v;
    }
}

// ---------------- fused 3x3 depthwise conv (bf16 in/out) + BN stats ----------------
__global__ __launch_bounds__(256) void conv3s_kernel(const ushort* __restrict__ Qbf,
                                                     const float* __restrict__ enh_w,
                                                     ushort* __restrict__ QEbf,
                                                     float* __restrict__ ssum,
                                                     float* __restrict__ ssq) {
    const int t = threadIdx.x;
    const int c0 = t * 2;
    const int xpos = blockIdx.x;
    const int byc = blockIdx.y;
    const int b = byc >> 2, yc = byc & 3;
    const int y0 = yc * 14;

    float wgt[9][2];
    #pragma unroll
    for (int tap = 0; tap < 9; ++tap) {
        wgt[tap][0] = enh_w[c0 * 9 + tap];
        wgt[tap][1] = enh_w[(c0 + 1) * 9 + tap];
    }
    const size_t base = (size_t)b * NTOK * CDIM + c0;

    float2 win[3][3];
    auto ldrow = [&](int yy, float2* dst) {
        #pragma unroll
        for (int dx = 0; dx < 3; ++dx) {
            int xx = xpos + dx - 1;
            bool ok = (yy >= 0 && yy < HW && xx >= 0 && xx < HW);
            if (ok) {
                ushort2 uv = *(const ushort2*)(Qbf + base + ((size_t)(yy * HW + xx) << 9));
                dst[dx] = make_float2(bf2f(uv.x), bf2f(uv.y));
            } else {
                dst[dx] = make_float2(0.f, 0.f);
            }
        }
    };
    ldrow(y0 - 1, win[0]);
    ldrow(y0,     win[1]);

    float s1a = 0.f, s2a = 0.f, s1b = 0.f, s2b = 0.f;
    #pragma unroll
    for (int i = 0; i < 14; ++i) {
        int y = y0 + i;
        ldrow(y + 1, win[(i + 2) % 3]);
        float a0 = 0.f, a1 = 0.f;
        #pragma unroll
        for (int dy = 0; dy < 3; ++dy) {
            float2* row = win[(i + dy) % 3];
            #pragma unroll
            for (int dx = 0; dx < 3; ++dx) {
                a0 = fmaf(row[dx].x, wgt[dy * 3 + dx][0], a0);
                a1 = fmaf(row[dx].y, wgt[dy * 3 + dx][1], a1);
            }
        }
        ushort2 o; o.x = f2bf(a0); o.y = f2bf(a1);
        *(ushort2*)(QEbf + base + ((size_t)(y * HW + xpos) << 9)) = o;
        s1a += a0; s2a += a0 * a0;
        s1b += a1; s2b += a1 * a1;
    }
    atomicAdd(&ssum[c0], s1a);     atomicAdd(&ssq[c0], s2a);
    atomicAdd(&ssum[c0 + 1], s1b); atomicAdd(&ssq[c0 + 1], s2b);
}

// ---------------- kvred v4: zero-LDS register MFMA GEMM, 14 chunks, split PKV --------
__global__ __launch_bounds__(256) void kvred4_kernel(const ushort* __restrict__ KF,
                                                     const ushort* __restrict__ Vbf,
                                                     float* __restrict__ PKV_A,
                                                     float* __restrict__ PKV_B) {
    const int bh = blockIdx.x, chunk = blockIdx.y;
    const int b = bh >> 3, head = bh & 7;
    const int t = threadIdx.x;
    const int w = t >> 6, l = t & 63;
    const int lr = l & 15;
    const int ns = (l >> 4) * 8;

    const int nbase = b * NTOK + chunk * 224;
    const ushort* kf0 = KF  + ((size_t)(nbase + ns)) * 1024 + head * 128 + (w * 32 + lr);
    const ushort* vb0 = Vbf + ((size_t)(nbase + ns)) * 512  + head * 64  + lr;

    short8 ones;
    #pragma unroll
    for (int j = 0; j < 8; ++j) ones[j] = (lr == 0) ? (short)0x3F80 : (short)0;

    f32x4 acc[2][5] = {};
    for (int tile = 0; tile < 7; ++tile) {
        union { uint u[4]; short8 s; } ua[2], ub[4];
        #pragma unroll
        for (int i = 0; i < 2; ++i) {
            #pragma unroll
            for (int j = 0; j < 4; ++j) {
                uint lo = kf0[i * 16 + (size_t)(2 * j) * 1024];
                uint hi = kf0[i * 16 + (size_t)(2 * j + 1) * 1024];
                ua[i].u[j] = lo | (hi << 16);
            }
        }
        #pragma unroll
        for (int j5 = 0; j5 < 4; ++j5) {
            #pragma unroll
            for (int j = 0; j < 4; ++j) {
                uint lo = vb0[j5 * 16 + (size_t)(2 * j) * 512];
                uint hi = vb0[j5 * 16 + (size_t)(2 * j + 1) * 512];
                ub[j5].u[j] = lo | (hi << 16);
            }
        }
        #pragma unroll
        for (int i = 0; i < 2; ++i) {
            #pragma unroll
            for (int j5 = 0; j5 < 4; ++j5)
                acc[i][j5] = __builtin_amdgcn_mfma_f32_16x16x32_bf16(ua[i].s, ub[j5].s, acc[i][j5], 0, 0, 0);
            acc[i][4] = __builtin_amdgcn_mfma_f32_16x16x32_bf16(ua[i].s, ones, acc[i][4], 0, 0, 0);
        }
        kf0 += (size_t)32 * 1024;
        vb0 += (size_t)32 * 512;
    }
    float* dstb = (chunk < 7)
        ? (PKV_A + ((size_t)(chunk * 64 + bh)) * 8320)
        : (PKV_B + ((size_t)((chunk - 7) * 64 + bh)) * 8320);
    #pragma unroll
    for (int i = 0; i < 2; ++i) {
        int d0 = w * 32 + i * 16 + (l >> 4) * 4;
        #pragma unroll
        for (int j = 0; j < 5; ++j) {
            int e = j * 16 + lr;
            if (j < 4 || e == 64)
                *(f32x4*)(dstb + (size_t)e * 128 + d0) = acc[i][j];
        }
    }
}

// ---------------- reduce split partials -> pre-swizzled bf16 BT image [bh][80][128] -----
__global__ __launch_bounds__(256) void kvreduce2_kernel(const float* __restrict__ PKV_A,
                                                        const float* __restrict__ PKV_B,
                                                        ushort* __restrict__ kvTbf) {
    int gid = blockIdx.x * 256 + threadIdx.x;
    const float inv_n = 1.0f / (float)NTOK;
    int bh = gid / 10240;
    int r  = gid - bh * 10240;
    int row = r >> 7, dcol = r & 127;
    int dlog = (((dcol >> 3) ^ (row & 7)) << 3) | (dcol & 7);
    float s = 0.f;
    if (row < 66) {
        int rsel, dsel;
        if (row < 64) { rsel = row; dsel = (row >= 32) ? (dlog ^ 64) : dlog; }
        else          { rsel = 64;  dsel = (row == 65) ? (dlog ^ 64) : dlog; }
        size_t idx = (size_t)bh * 8320 + rsel * 128 + dsel;
        #pragma unroll
        for (int c = 0; c < 7; ++c) s += PKV_A[(size_t)c * 532480 + idx];
        #pragma unroll
        for (int c = 0; c < 7; ++c) s += PKV_B[(size_t)c * 532480 + idx];
    }
    kvTbf[gid] = (row < 66) ? f2bf(s * inv_n) : (ushort)0;
}

// ---------------- attention apply via MFMA (qfin + BN-prep fused) -------------------
__global__ __launch_bounds__(256) void attn_mfma_kernel(const ushort* __restrict__ Qbf,
                                                        const ushort* __restrict__ QEbf,
                                                        const ushort* __restrict__ kvTbf,
                                                        const float* __restrict__ power,
                                                        const float* __restrict__ ssum,
                                                        const float* __restrict__ ssq,
                                                        const float* __restrict__ bn_g,
                                                        const float* __restrict__ bn_b,
                                                        const float* __restrict__ invs,
                                                        const float* __restrict__ ewp,
                                                        ushort* __restrict__ ATTbf) {
    __shared__ ushort QF[64 * 128];
    __shared__ ushort BT[80 * 128];
    const int bh = blockIdx.x, tb = blockIdx.y;
    const int b = bh >> 3, head = bh & 7;
    const int t = threadIdx.x;
    const int w = t >> 6, l = t & 63;

    #pragma unroll
    for (int i = 0; i < 5; ++i) {
        int f = i * 256 + t;
        gload_lds16(kvTbf + (size_t)bh * 10240 + f * 8, BT + f * 8);
    }

    const int c = l, hc = head * 64 + c;
    const float p = power[hc];
    const float invM = 1.0f / (float)MTOT;
    float mean = ssum[hc] * invM;
    float var  = ssq[hc] * invM - mean * mean;
    const float ac = bn_g[hc] * rsqrtf(var + 1e-5f);
    const float bc = bn_b[hc] - mean * ac;
    const float iv = invs[hc], ew = ewp[0];
    #pragma unroll
    for (int i = 0; i < 16; ++i) {
        int tok = i * 4 + w;
        size_t off = ((size_t)(b * NTOK + tb * 64 + tok)) * CDIM + hc;
        float q = bf2f(Qbf[off]);
        float qe = bf2f(QEbf[off]);
        q = (q + ew * fmaxf(fmaf(ac, qe, bc), 0.f)) * iv;
        float ax = fabsf(q);
        float tp = ax > 0.f ? __powf(ax, p) : 0.f;
        float qp = q > 0.f ? tp : 0.f;
        float qn = q < 0.f ? tp : 0.f;
        int sw = tok & 7;
        QF[tok * 128 + (((c >> 3) ^ sw) * 8) + (c & 7)]       = f2bf(qp);
        QF[tok * 128 + ((((c >> 3) + 8) ^ sw) * 8) + (c & 7)] = f2bf(qn);
    }
    __syncthreads();

    f32x4 acc[5] = {};
    #pragma unroll
    for (int kk = 0; kk < 4; ++kk) {
        int sbase = kk * 4 + (l >> 4);
        int rowa = w * 16 + (l & 15);
        short8 af = *(const short8*)&QF[rowa * 128 + ((sbase ^ (rowa & 7)) * 8)];
        #pragma unroll
        for (int j = 0; j < 5; ++j) {
            int rowb = j * 16 + (l & 15);
            short8 bf = *(const short8*)&BT[rowb * 128 + ((sbase ^ (rowb & 7)) * 8)];
            acc[j] = __builtin_amdgcn_mfma_f32_16x16x32_bf16(af, bf, acc[j], 0, 0, 0);
        }
    }
    __syncthreads();

    ushort* Oout = QF;
    #pragma unroll
    for (int rr = 0; rr < 4; ++rr) {
        float ssim = __shfl(acc[4][rr], (l & 48));
        float sopp = __shfl(acc[4][rr], (l & 48) + 1);
        float zs = 1.f / (ssim + 1e-6f);
        float zo = 1.f / (sopp + 1e-6f);
        int tokl = w * 16 + (l >> 4) * 4 + rr;
        #pragma unroll
        for (int j = 0; j < 4; ++j) {
            int e = j * 16 + (l & 15);
            Oout[tokl * 64 + e] = f2bf(acc[j][rr] * (j < 2 ? zs : zo));
        }
    }
    __syncthreads();

    #pragma unroll
    for (int i = 0; i < 2; ++i) {
        int idx = i * 256 + t;
        int tokl = idx >> 3, ch = (idx & 7) * 8;
        short8 vv = *(short8*)&Oout[tokl * 64 + ch];
        *(short8*)&ATTbf[((size_t)(b * NTOK + tb * 64 + tokl)) * CDIM + head * 64 + ch] = vv;
    }
}

// ---------------- v 5x5 depthwise conv (bf16 V) + gate (bf16 ATT, bf16 G) --------------
__global__ __launch_bounds__(256) void voutg2_kernel(const ushort* __restrict__ Vbf,
                                                     const ushort* __restrict__ ATTbf,
                                                     const ushort* __restrict__ Gbf,
                                                     const float* __restrict__ dwc_w,
                                                     const float* __restrict__ dwc_b,
                                                     ushort* __restrict__ PRE) {
    const int t = threadIdx.x;
    const int c0 = t * 2;
    const int xpos = blockIdx.x;
    const int byc = blockIdx.y;
    const int b = byc >> 2, yc = byc & 3;
    const int y0 = yc * 14;
    const int dch = c0 & 63;

    float wgt[25][2];
    #pragma unroll
    for (int tap = 0; tap < 25; ++tap) {
        wgt[tap][0] = dwc_w[dch * 25 + tap];
        wgt[tap][1] = dwc_w[(dch + 1) * 25 + tap];
    }
    const float bias0 = dwc_b[dch], bias1 = dwc_b[dch + 1];
    const size_t base = (size_t)b * NTOK * CDIM + c0;

    float2 win[5][5];
    auto ldrow = [&](int yy, float2* dst) {
        #pragma unroll
        for (int dx = 0; dx < 5; ++dx) {
            int xx = xpos + dx - 2;
            bool ok = (yy >= 0 && yy < HW && xx >= 0 && xx < HW);
            if (ok) {
                ushort2 uv = *(const ushort2*)(Vbf + base + ((size_t)(yy * HW + xx) << 9));
                dst[dx] = make_float2(bf2f(uv.x), bf2f(uv.y));
            } else {
                dst[dx] = make_float2(0.f, 0.f);
            }
        }
    };
    ldrow(y0 - 2, win[0]);
    ldrow(y0 - 1, win[1]);
    ldrow(y0,     win[2]);
    ldrow(y0 + 1, win[3]);

    #pragma unroll
    for (int i = 0; i < 14; ++i) {
        int y = y0 + i;
        ldrow(y + 2, win[(i + 4) % 5]);
        float a0 = bias0, a1 = bias1;
        #pragma unroll
        for (int dy = 0; dy < 5; ++dy) {
            float2* row = win[(i + dy) % 5];
            #pragma unroll
            for (int dx = 0; dx < 5; ++dx) {
                a0 = fmaf(row[dx].x, wgt[dy * 5 + dx][0], a0);
                a1 = fmaf(row[dx].y, wgt[dy * 5 + dx][1], a1);
            }
        }
        size_t oidx = base + ((size_t)(y * HW + xpos) << 9);
        ushort2 au = *(const ushort2*)(ATTbf + oidx);
        ushort2 gu = *(const ushort2*)(Gbf + oidx);
        ushort2 o;
        o.x = f2bf((bf2f(au.x) + a0) * bf2f(gu.x));
        o.y = f2bf((bf2f(au.y) + a1) * bf2f(gu.y));
        *(ushort2*)(PRE + oidx) = o;
    }
}

extern "C" void kernel_launch(void* const* d_in, const int* in_sizes, int n_in,
                              void* d_out, int out_size, void* d_ws, size_t ws_size,
                              hipStream_t stream) {
    const float* x      = (const float*)d_in[0];
    const float* qg_w   = (const float*)d_in[1];
    const float* kv_w   = (const float*)d_in[2];
    const float* proj_w = (const float*)d_in[3];
    const float* proj_b = (const float*)d_in[4];
    const float* dwc_w  = (const float*)d_in[5];
    const float* dwc_b  = (const float*)d_in[6];
    const float* power_p= (const float*)d_in[7];
    const float* scale_p= (const float*)d_in[8];
    const float* enh_w  = (const float*)d_in[9];
    const float* bn_g   = (const float*)d_in[10];
    const float* bn_b   = (const float*)d_in[11];
    const float* ew_p   = (const float*)d_in[12];
    const float* pos    = (const float*)d_in[13];

    const size_t NELEM = (size_t)MTOT * CDIM;   // 12,845,056
    float* ws    = (float*)d_ws;
    ushort* Qbf  = (ushort*)ws;
    ushort* Gbf  = (ushort*)(ws + NELEM);
    float*  PKV_A= ws + NELEM + NELEM / 2;
    ushort* KFbf = (ushort*)(ws + 2 * NELEM);
    ushort* PREbf= (ushort*)(ws + 2 * NELEM);
    ushort* Vbf  = (ushort*)(ws + 3 * NELEM);
    ushort* ATTbf= (ushort*)(ws + 3 * NELEM + NELEM / 2);
    ushort* Xbf  = (ushort*)(ws + 4 * NELEM);
    ushort* QEbf = (ushort*)(ws + 4 * NELEM);
    float*  PKV_B= ws + 4 * NELEM + NELEM / 2;
    float* SMALL = ws + 5 * NELEM;
    float* ssum  = SMALL;               // 512
    float* ssq   = SMALL + 512;         // 512
    ushort* kvTbf= (ushort*)(SMALL + 9216);
    float* invs  = SMALL + 533504;
    float* powr  = SMALL + 534016;
    ushort* Wqg  = (ushort*)(SMALL + 535552);
    ushort* Wkv  = (ushort*)(SMALL + 797696);
    ushort* Wproj= (ushort*)(SMALL + 1059840);

    hipMemsetAsync(SMALL, 0, (size_t)1024 * sizeof(float), stream);

    cvt_bf16_kernel<<<12544, 256, 0, stream>>>(x, Xbf, 3211264);
    cvt_weights_kernel<<<1282, 256, 0, stream>>>(qg_w, kv_w, proj_w, Wqg, Wkv, Wproj,
                                                 scale_p, power_p, invs, powr);

    mgemm_qgkv<<<3136, 256, 0, stream>>>(Xbf, Wqg, Wkv, Qbf, Gbf, KFbf, Vbf, pos, invs, powr);

    dim3 cgrid(56, 32);
    conv3s_kernel<<<cgrid, 256, 0, stream>>>(Qbf, enh_w, QEbf, ssum, ssq);

    kvred4_kernel<<<dim3(64, 14), 256, 0, stream>>>(KFbf, Vbf, PKV_A, PKV_B);
    kvreduce2_kernel<<<2560, 256, 0, stream>>>(PKV_A, PKV_B, kvTbf);

    attn_mfma_kernel<<<dim3(64, 49), 256, 0, stream>>>(Qbf, QEbf, kvTbf, powr,
                                                       ssum, ssq, bn_g, bn_b,
                                                       invs, ew_p, ATTbf);

    voutg2_kernel<<<cgrid, 256, 0, stream>>>(Vbf, ATTbf, Gbf, dwc_w, dwc_b, PREbf);

    mgemm_proj<<<784, 256, 0, stream>>>(PREbf, Wproj, (float*)d_out, proj_b);
}

// Round 19
// 449.334 us; speedup vs baseline: 1.2042x; 1.0284x over previous
//
#include <hip/hip_runtime.h>
#include <hip/hip_bf16.h>
#include <math.h>

#define CDIM 512
#define NTOK 3136
#define BATCH 8
#define MTOT (BATCH*NTOK)   // 25088
#define NHEAD 8
#define DHEAD 64
#define HW 56

typedef __attribute__((ext_vector_type(8))) short short8;
typedef __attribute__((ext_vector_type(4))) float f32x4;

__device__ __forceinline__ ushort f2bf(float f) {
    union { float f; unsigned int u; } v; v.f = f;
    unsigned int u = v.u + 0x7FFFu + ((v.u >> 16) & 1u);
    return (ushort)(u >> 16);
}
__device__ __forceinline__ float bf2f(ushort u) {
    union { unsigned int u; float f; } v; v.u = ((unsigned int)u) << 16;
    return v.f;
}

__device__ __forceinline__ void gload_lds16(const void* g, void* lds) {
    __builtin_amdgcn_global_load_lds((const __attribute__((address_space(1))) void*)g,
                                     (__attribute__((address_space(3))) void*)lds,
                                     16, 0, 0);
}

// ---------------- all input conversions + prep in ONE launch ----------------
// blocks [0,12544): x -> Xbf ; [12544,13824): weights ; 13824/13825: prep
__global__ __launch_bounds__(256) void cvt_all_kernel(const float* __restrict__ x,
                                                      ushort* __restrict__ Xbf,
                                                      const float* __restrict__ qg_w,
                                                      const float* __restrict__ kv_w,
                                                      const float* __restrict__ proj_w,
                                                      ushort* __restrict__ Wqg,
                                                      ushort* __restrict__ Wkv,
                                                      ushort* __restrict__ Wproj,
                                                      const float* __restrict__ scale_p,
                                                      const float* __restrict__ power_p,
                                                      float* __restrict__ inv_scale,
                                                      float* __restrict__ power) {
    int blk = blockIdx.x;
    if (blk < 12544) {
        int i = blk * 256 + threadIdx.x;
        float4 f = ((const float4*)x)[i];
        ushort4 o;
        o.x = f2bf(f.x); o.y = f2bf(f.y); o.z = f2bf(f.z); o.w = f2bf(f.w);
        ((ushort4*)Xbf)[i] = o;
        return;
    }
    if (blk >= 13824) {
        int c = (blk - 13824) * 256 + threadIdx.x;
        float s = log1pf(expf(scale_p[c]));
        inv_scale[c] = 1.0f / s;
        power[c] = 1.0f + 4.0f / (1.0f + expf(-power_p[c]));
        return;
    }
    int i = (blk - 12544) * 256 + threadIdx.x;
    const float* src; ushort* dst; int idx;
    if (i < 131072)      { src = qg_w;   dst = Wqg;   idx = i; }
    else if (i < 262144) { src = kv_w;   dst = Wkv;   idx = i - 131072; }
    else                 { src = proj_w; dst = Wproj; idx = i - 262144; }
    float4 f = ((const float4*)src)[idx];
    ushort4 o;
    o.x = f2bf(f.x); o.y = f2bf(f.y); o.z = f2bf(f.z); o.w = f2bf(f.w);
    ((ushort4*)dst)[idx] = o;
}

// ---------------- merged qg+kv GEMM: BK=32 x 3-buffer counted-vmcnt pipeline (48KB),
// 3 blocks/CU, 16B-store epilogue. grid 3136; idp=(bid&7)*392+(bid>>3); mb=idp>>4, ob=idp&15.
__global__ __launch_bounds__(256, 3) void mgemm_qgkv(const ushort* __restrict__ A,
                                                     const ushort* __restrict__ Wqg,
                                                     const ushort* __restrict__ Wkv,
                                                     ushort* __restrict__ Qout,
                                                     ushort* __restrict__ Gout,
                                                     ushort* __restrict__ KFout,
                                                     ushort* __restrict__ Vout,
                                                     const float* __restrict__ pos,
                                                     const float* __restrict__ invs,
                                                     const float* __restrict__ powr) {
    __shared__ __align__(16) char smem[49152];
    ushort* At = (ushort*)smem;               // [3][128*32]
    ushort* Bt = (ushort*)(smem + 24576);     // [3][128*32]
    float*  Osh = (float*)smem;               // epilogue alias [64][128]

    const int t = threadIdx.x;
    const int w = t >> 6, l = t & 63;
    const int wr = w >> 1, wc = w & 1;

    const int bid = blockIdx.x;
    const int idp = (bid & 7) * 392 + (bid >> 3);
    const int mb = idp >> 4, ob = idp & 15;
    const int m0 = mb * 128;
    const ushort* Bp = (ob < 8) ? (Wqg + (size_t)ob * 128 * CDIM)
                                : (Wkv + (size_t)(ob - 8) * 128 * CDIM);

    auto stage = [&](int buf, int ks) {
        const int k0 = ks * 32;
        #pragma unroll
        for (int i = 0; i < 2; ++i) {
            int f = t + i * 256;
            int row = f >> 2, ps = f & 3;
            int ls = ps ^ ((row >> 1) & 3);
            gload_lds16(A + (size_t)(m0 + row) * CDIM + k0 + ls * 8, At + buf * 4096 + f * 8);
            gload_lds16(Bp + (size_t)row * CDIM + k0 + ls * 8, Bt + buf * 4096 + f * 8);
        }
    };

    f32x4 acc[4][4] = {};
    stage(0, 0);
    stage(1, 1);
    const int sl4 = l >> 4;
    for (int ks = 0; ks < 16; ++ks) {
        if (ks < 15) asm volatile("s_waitcnt vmcnt(4)" ::: "memory");
        else         asm volatile("s_waitcnt vmcnt(0)" ::: "memory");
        __builtin_amdgcn_s_barrier();
        if (ks + 2 < 16) stage((ks + 2) % 3, ks + 2);
        const int cur = ks % 3;
        short8 af[4], bfr[4];
        #pragma unroll
        for (int i = 0; i < 4; ++i) {
            int row = wr * 64 + i * 16 + (l & 15);
            int ph = sl4 ^ ((row >> 1) & 3);
            af[i] = *(const short8*)&At[cur * 4096 + row * 32 + ph * 8];
            int rowb = wc * 64 + i * 16 + (l & 15);
            int phb = sl4 ^ ((rowb >> 1) & 3);
            bfr[i] = *(const short8*)&Bt[cur * 4096 + rowb * 32 + phb * 8];
        }
        #pragma unroll
        for (int i = 0; i < 4; ++i)
            #pragma unroll
            for (int j = 0; j < 4; ++j)
                acc[i][j] = __builtin_amdgcn_mfma_f32_16x16x32_bf16(af[i], bfr[j], acc[i][j], 0, 0, 0);
    }
    __syncthreads();

    const int colbase = ob * 128;
    #pragma unroll
    for (int p = 0; p < 2; ++p) {
        if (wr == p) {
            #pragma unroll
            for (int i = 0; i < 4; ++i)
                #pragma unroll
                for (int j = 0; j < 4; ++j)
                    #pragma unroll
                    for (int rr = 0; rr < 4; ++rr) {
                        int row = i * 16 + (l >> 4) * 4 + rr;
                        int col = wc * 64 + j * 16 + (l & 15);
                        int pc = col ^ (((row >> 2) & 1) << 4);
                        Osh[row * 128 + pc] = acc[i][j][rr];
                    }
        }
        __syncthreads();
        #pragma unroll
        for (int q = 0; q < 4; ++q) {
            int fi = q * 256 + t;
            int rl = fi >> 4;
            int c8 = (fi & 15) * 8;
            int xo = ((rl >> 2) & 1) << 4;
            float4 va = *(float4*)&Osh[rl * 128 + (c8 ^ xo)];
            float4 vb = *(float4*)&Osh[rl * 128 + ((c8 + 4) ^ xo)];
            int m = m0 + p * 64 + rl;
            if (colbase < 512) {
                union { ushort u[8]; short8 s; } o;
                o.u[0]=f2bf(va.x); o.u[1]=f2bf(va.y); o.u[2]=f2bf(va.z); o.u[3]=f2bf(va.w);
                o.u[4]=f2bf(vb.x); o.u[5]=f2bf(vb.y); o.u[6]=f2bf(vb.z); o.u[7]=f2bf(vb.w);
                *(short8*)&Qout[(size_t)m * CDIM + colbase + c8] = o.s;
            } else if (colbase < 1024) {
                union { ushort u[8]; short8 s; } o;
                o.u[0]=f2bf(va.x); o.u[1]=f2bf(va.y); o.u[2]=f2bf(va.z); o.u[3]=f2bf(va.w);
                o.u[4]=f2bf(vb.x); o.u[5]=f2bf(vb.y); o.u[6]=f2bf(vb.z); o.u[7]=f2bf(vb.w);
                *(short8*)&Gout[(size_t)m * CDIM + colbase - 512 + c8] = o.s;
            } else if (colbase < 1536) {
                int n = m % NTOK;
                int oc = colbase - 1024 + c8;
                const float* pp = &pos[(size_t)n * CDIM + oc];
                float4 pva = *(const float4*)pp;
                float4 pvb = *(const float4*)(pp + 4);
                float4 iva = *(const float4*)&invs[oc];
                float4 ivb = *(const float4*)&invs[oc + 4];
                float4 pwa = *(const float4*)&powr[oc];
                float4 pwb = *(const float4*)&powr[oc + 4];
                float kx[8], tp[8];
                kx[0]=(va.x+pva.x)*iva.x; kx[1]=(va.y+pva.y)*iva.y;
                kx[2]=(va.z+pva.z)*iva.z; kx[3]=(va.w+pva.w)*iva.w;
                kx[4]=(vb.x+pvb.x)*ivb.x; kx[5]=(vb.y+pvb.y)*ivb.y;
                kx[6]=(vb.z+pvb.z)*ivb.z; kx[7]=(vb.w+pvb.w)*ivb.w;
                tp[0]=__powf(fabsf(kx[0]),pwa.x); tp[1]=__powf(fabsf(kx[1]),pwa.y);
                tp[2]=__powf(fabsf(kx[2]),pwa.z); tp[3]=__powf(fabsf(kx[3]),pwa.w);
                tp[4]=__powf(fabsf(kx[4]),pwb.x); tp[5]=__powf(fabsf(kx[5]),pwb.y);
                tp[6]=__powf(fabsf(kx[6]),pwb.z); tp[7]=__powf(fabsf(kx[7]),pwb.w);
                union { ushort u[8]; short8 s; } up, un;
                #pragma unroll
                for (int e = 0; e < 8; ++e) {
                    ushort bb = f2bf(tp[e]);
                    up.u[e] = kx[e] > 0.f ? bb : (ushort)0;
                    un.u[e] = kx[e] < 0.f ? bb : (ushort)0;
                }
                ushort* dst = KFout + (size_t)m * 1024 + ((oc >> 6) << 7) + (oc & 63);
                *(short8*)dst = up.s;
                *(short8*)(dst + 64) = un.s;
            } else {
                union { ushort u[8]; short8 s; } o;
                o.u[0]=f2bf(va.x); o.u[1]=f2bf(va.y); o.u[2]=f2bf(va.z); o.u[3]=f2bf(va.w);
                o.u[4]=f2bf(vb.x); o.u[5]=f2bf(vb.y); o.u[6]=f2bf(vb.z); o.u[7]=f2bf(vb.w);
                *(short8*)&Vout[(size_t)m * CDIM + colbase - 1536 + c8] = o.s;
            }
        }
        __syncthreads();
    }
}

// ---------------- proj GEMM: BK=32 x 3-buffer counted-vmcnt pipeline, XOR fp32 epilogue --
__global__ __launch_bounds__(256, 3) void mgemm_proj(const ushort* __restrict__ A,
                                                     const ushort* __restrict__ W,
                                                     float* __restrict__ out,
                                                     const float* __restrict__ pb) {
    __shared__ __align__(16) char smem[49152];
    ushort* At = (ushort*)smem;
    ushort* Bt = (ushort*)(smem + 24576);
    float*  Osh = (float*)smem;               // [64][128] alias

    const int t = threadIdx.x;
    const int w = t >> 6, l = t & 63;
    const int wr = w >> 1, wc = w & 1;

    const int bid = blockIdx.x;
    const int idp = (bid & 7) * 98 + (bid >> 3);
    const int mb = idp >> 2, ob = idp & 3;
    const int m0 = mb * 128;
    const ushort* Bp = W + (size_t)ob * 128 * CDIM;

    auto stage = [&](int buf, int ks) {
        const int k0 = ks * 32;
        #pragma unroll
        for (int i = 0; i < 2; ++i) {
            int f = t + i * 256;
            int row = f >> 2, ps = f & 3;
            int ls = ps ^ ((row >> 1) & 3);
            gload_lds16(A + (size_t)(m0 + row) * CDIM + k0 + ls * 8, At + buf * 4096 + f * 8);
            gload_lds16(Bp + (size_t)row * CDIM + k0 + ls * 8, Bt + buf * 4096 + f * 8);
        }
    };

    f32x4 acc[4][4] = {};
    stage(0, 0);
    stage(1, 1);
    const int sl4 = l >> 4;
    for (int ks = 0; ks < 16; ++ks) {
        if (ks < 15) asm volatile("s_waitcnt vmcnt(4)" ::: "memory");
        else         asm volatile("s_waitcnt vmcnt(0)" ::: "memory");
        __builtin_amdgcn_s_barrier();
        if (ks + 2 < 16) stage((ks + 2) % 3, ks + 2);
        const int cur = ks % 3;
        short8 af[4], bfr[4];
        #pragma unroll
        for (int i = 0; i < 4; ++i) {
            int row = wr * 64 + i * 16 + (l & 15);
            int ph = sl4 ^ ((row >> 1) & 3);
            af[i] = *(const short8*)&At[cur * 4096 + row * 32 + ph * 8];
            int rowb = wc * 64 + i * 16 + (l & 15);
            int phb = sl4 ^ ((rowb >> 1) & 3);
            bfr[i] = *(const short8*)&Bt[cur * 4096 + rowb * 32 + phb * 8];
        }
        #pragma unroll
        for (int i = 0; i < 4; ++i)
            #pragma unroll
            for (int j = 0; j < 4; ++j)
                acc[i][j] = __builtin_amdgcn_mfma_f32_16x16x32_bf16(af[i], bfr[j], acc[i][j], 0, 0, 0);
    }
    __syncthreads();

    const int colbase = ob * 128;
    #pragma unroll
    for (int p = 0; p < 2; ++p) {
        if (wr == p) {
            #pragma unroll
            for (int i = 0; i < 4; ++i)
                #pragma unroll
                for (int j = 0; j < 4; ++j)
                    #pragma unroll
                    for (int rr = 0; rr < 4; ++rr) {
                        int row = i * 16 + (l >> 4) * 4 + rr;
                        int col = wc * 64 + j * 16 + (l & 15);
                        int pc = col ^ (((row >> 2) & 1) << 4);
                        Osh[row * 128 + pc] = acc[i][j][rr];
                    }
        }
        __syncthreads();
        #pragma unroll
        for (int q = 0; q < 8; ++q) {
            int fi = q * 256 + t;
            int rl = fi >> 5, c4 = (fi & 31) * 4;
            int pc4 = c4 ^ (((rl >> 2) & 1) << 4);
            float4 v = *(float4*)&Osh[rl * 128 + pc4];
            float4 b4 = *(const float4*)&pb[colbase + c4];
            v.x += b4.x; v.y += b4.y; v.z += b4.z; v.w += b4.w;
            *(float4*)&out[(size_t)(m0 + p * 64 + rl) * CDIM + colbase + c4] = v;
        }
        __syncthreads();
    }
}

// ---------------- FUSED mid: kvred4 (blocks 0..895) || conv3s (blocks 896..2687) -------
__global__ __launch_bounds__(256) void fused_mid_kernel(const ushort* __restrict__ KF,
                                                        const ushort* __restrict__ Vbf,
                                                        float* __restrict__ PKV_A,
                                                        float* __restrict__ PKV_B,
                                                        const ushort* __restrict__ Qbf,
                                                        const float* __restrict__ enh_w,
                                                        ushort* __restrict__ QEbf,
                                                        float* __restrict__ ssum,
                                                        float* __restrict__ ssq) {
    const int blk = blockIdx.x;
    const int t = threadIdx.x;
    if (blk < 896) {
        // ---- kvred4 ----
        const int bh = blk & 63, chunk = blk >> 6;      // 0..13
        const int b = bh >> 3, head = bh & 7;
        const int w = t >> 6, l = t & 63;
        const int lr = l & 15;
        const int ns = (l >> 4) * 8;

        const int nbase = b * NTOK + chunk * 224;
        const ushort* kf0 = KF  + ((size_t)(nbase + ns)) * 1024 + head * 128 + (w * 32 + lr);
        const ushort* vb0 = Vbf + ((size_t)(nbase + ns)) * 512  + head * 64  + lr;

        short8 ones;
        #pragma unroll
        for (int j = 0; j < 8; ++j) ones[j] = (lr == 0) ? (short)0x3F80 : (short)0;

        f32x4 acc[2][5] = {};
        for (int tile = 0; tile < 7; ++tile) {
            union { uint u[4]; short8 s; } ua[2], ub[4];
            #pragma unroll
            for (int i = 0; i < 2; ++i) {
                #pragma unroll
                for (int j = 0; j < 4; ++j) {
                    uint lo = kf0[i * 16 + (size_t)(2 * j) * 1024];
                    uint hi = kf0[i * 16 + (size_t)(2 * j + 1) * 1024];
                    ua[i].u[j] = lo | (hi << 16);
                }
            }
            #pragma unroll
            for (int j5 = 0; j5 < 4; ++j5) {
                #pragma unroll
                for (int j = 0; j < 4; ++j) {
                    uint lo = vb0[j5 * 16 + (size_t)(2 * j) * 512];
                    uint hi = vb0[j5 * 16 + (size_t)(2 * j + 1) * 512];
                    ub[j5].u[j] = lo | (hi << 16);
                }
            }
            #pragma unroll
            for (int i = 0; i < 2; ++i) {
                #pragma unroll
                for (int j5 = 0; j5 < 4; ++j5)
                    acc[i][j5] = __builtin_amdgcn_mfma_f32_16x16x32_bf16(ua[i].s, ub[j5].s, acc[i][j5], 0, 0, 0);
                acc[i][4] = __builtin_amdgcn_mfma_f32_16x16x32_bf16(ua[i].s, ones, acc[i][4], 0, 0, 0);
            }
            kf0 += (size_t)32 * 1024;
            vb0 += (size_t)32 * 512;
        }
        float* dstb = (chunk < 7)
            ? (PKV_A + ((size_t)(chunk * 64 + bh)) * 8320)
            : (PKV_B + ((size_t)((chunk - 7) * 64 + bh)) * 8320);
        #pragma unroll
        for (int i = 0; i < 2; ++i) {
            int d0 = w * 32 + i * 16 + (l >> 4) * 4;
            #pragma unroll
            for (int j = 0; j < 5; ++j) {
                int e = j * 16 + lr;
                if (j < 4 || e == 64)
                    *(f32x4*)(dstb + (size_t)e * 128 + d0) = acc[i][j];
            }
        }
        return;
    }
    // ---- conv3s ----
    {
        const int idx = blk - 896;
        const int xpos = idx % 56;
        const int byc = idx / 56;
        const int c0 = t * 2;
        const int b = byc >> 2, yc = byc & 3;
        const int y0 = yc * 14;

        float wgt[9][2];
        #pragma unroll
        for (int tap = 0; tap < 9; ++tap) {
            wgt[tap][0] = enh_w[c0 * 9 + tap];
            wgt[tap][1] = enh_w[(c0 + 1) * 9 + tap];
        }
        const size_t base = (size_t)b * NTOK * CDIM + c0;

        float2 win[3][3];
        auto ldrow = [&](int yy, float2* dst) {
            #pragma unroll
            for (int dx = 0; dx < 3; ++dx) {
                int xx = xpos + dx - 1;
                bool ok = (yy >= 0 && yy < HW && xx >= 0 && xx < HW);
                if (ok) {
                    ushort2 uv = *(const ushort2*)(Qbf + base + ((size_t)(yy * HW + xx) << 9));
                    dst[dx] = make_float2(bf2f(uv.x), bf2f(uv.y));
                } else {
                    dst[dx] = make_float2(0.f, 0.f);
                }
            }
        };
        ldrow(y0 - 1, win[0]);
        ldrow(y0,     win[1]);

        float s1a = 0.f, s2a = 0.f, s1b = 0.f, s2b = 0.f;
        #pragma unroll
        for (int i = 0; i < 14; ++i) {
            int y = y0 + i;
            ldrow(y + 1, win[(i + 2) % 3]);
            float a0 = 0.f, a1 = 0.f;
            #pragma unroll
            for (int dy = 0; dy < 3; ++dy) {
                float2* row = win[(i + dy) % 3];
                #pragma unroll
                for (int dx = 0; dx < 3; ++dx) {
                    a0 = fmaf(row[dx].x, wgt[dy * 3 + dx][0], a0);
                    a1 = fmaf(row[dx].y, wgt[dy * 3 + dx][1], a1);
                }
            }
            ushort2 o; o.x = f2bf(a0); o.y = f2bf(a1);
            *(ushort2*)(QEbf + base + ((size_t)(y * HW + xpos) << 9)) = o;
            s1a += a0; s2a += a0 * a0;
            s1b += a1; s2b += a1 * a1;
        }
        atomicAdd(&ssum[c0], s1a);     atomicAdd(&ssq[c0], s2a);
        atomicAdd(&ssum[c0 + 1], s1b); atomicAdd(&ssq[c0 + 1], s2b);
    }
}

// ---------------- reduce split partials -> pre-swizzled bf16 BT image [bh][80][128] -----
__global__ __launch_bounds__(256) void kvreduce2_kernel(const float* __restrict__ PKV_A,
                                                        const float* __restrict__ PKV_B,
                                                        ushort* __restrict__ kvTbf) {
    int gid = blockIdx.x * 256 + threadIdx.x;
    const float inv_n = 1.0f / (float)NTOK;
    int bh = gid / 10240;
    int r  = gid - bh * 10240;
    int row = r >> 7, dcol = r & 127;
    int dlog = (((dcol >> 3) ^ (row & 7)) << 3) | (dcol & 7);
    float s = 0.f;
    if (row < 66) {
        int rsel, dsel;
        if (row < 64) { rsel = row; dsel = (row >= 32) ? (dlog ^ 64) : dlog; }
        else          { rsel = 64;  dsel = (row == 65) ? (dlog ^ 64) : dlog; }
        size_t idx = (size_t)bh * 8320 + rsel * 128 + dsel;
        #pragma unroll
        for (int c = 0; c < 7; ++c) s += PKV_A[(size_t)c * 532480 + idx];
        #pragma unroll
        for (int c = 0; c < 7; ++c) s += PKV_B[(size_t)c * 532480 + idx];
    }
    kvTbf[gid] = (row < 66) ? f2bf(s * inv_n) : (ushort)0;
}

// ---------------- attention apply via MFMA (qfin + BN-prep fused) -------------------
__global__ __launch_bounds__(256) void attn_mfma_kernel(const ushort* __restrict__ Qbf,
                                                        const ushort* __restrict__ QEbf,
                                                        const ushort* __restrict__ kvTbf,
                                                        const float* __restrict__ power,
                                                        const float* __restrict__ ssum,
                                                        const float* __restrict__ ssq,
                                                        const float* __restrict__ bn_g,
                                                        const float* __restrict__ bn_b,
                                                        const float* __restrict__ invs,
                                                        const float* __restrict__ ewp,
                                                        ushort* __restrict__ ATTbf) {
    __shared__ ushort QF[64 * 128];
    __shared__ ushort BT[80 * 128];
    const int bh = blockIdx.x, tb = blockIdx.y;
    const int b = bh >> 3, head = bh & 7;
    const int t = threadIdx.x;
    const int w = t >> 6, l = t & 63;

    #pragma unroll
    for (int i = 0; i < 5; ++i) {
        int f = i * 256 + t;
        gload_lds16(kvTbf + (size_t)bh * 10240 + f * 8, BT + f * 8);
    }

    const int c = l, hc = head * 64 + c;
    const float p = power[hc];
    const float invM = 1.0f / (float)MTOT;
    float mean = ssum[hc] * invM;
    float var  = ssq[hc] * invM - mean * mean;
    const float ac = bn_g[hc] * rsqrtf(var + 1e-5f);
    const float bc = bn_b[hc] - mean * ac;
    const float iv = invs[hc], ew = ewp[0];
    #pragma unroll
    for (int i = 0; i < 16; ++i) {
        int tok = i * 4 + w;
        size_t off = ((size_t)(b * NTOK + tb * 64 + tok)) * CDIM + hc;
        float q = bf2f(Qbf[off]);
        float qe = bf2f(QEbf[off]);
        q = (q + ew * fmaxf(fmaf(ac, qe, bc), 0.f)) * iv;
        float ax = fabsf(q);
        float tp = ax > 0.f ? __powf(ax, p) : 0.f;
        float qp = q > 0.f ? tp : 0.f;
        float qn = q < 0.f ? tp : 0.f;
        int sw = tok & 7;
        QF[tok * 128 + (((c >> 3) ^ sw) * 8) + (c & 7)]       = f2bf(qp);
        QF[tok * 128 + ((((c >> 3) + 8) ^ sw) * 8) + (c & 7)] = f2bf(qn);
    }
    __syncthreads();

    f32x4 acc[5] = {};
    #pragma unroll
    for (int kk = 0; kk < 4; ++kk) {
        int sbase = kk * 4 + (l >> 4);
        int rowa = w * 16 + (l & 15);
        short8 af = *(const short8*)&QF[rowa * 128 + ((sbase ^ (rowa & 7)) * 8)];
        #pragma unroll
        for (int j = 0; j < 5; ++j) {
            int rowb = j * 16 + (l & 15);
            short8 bf = *(const short8*)&BT[rowb * 128 + ((sbase ^ (rowb & 7)) * 8)];
            acc[j] = __builtin_amdgcn_mfma_f32_16x16x32_bf16(af, bf, acc[j], 0, 0, 0);
        }
    }
    __syncthreads();

    ushort* Oout = QF;
    #pragma unroll
    for (int rr = 0; rr < 4; ++rr) {
        float ssim = __shfl(acc[4][rr], (l & 48));
        float sopp = __shfl(acc[4][rr], (l & 48) + 1);
        float zs = 1.f / (ssim + 1e-6f);
        float zo = 1.f / (sopp + 1e-6f);
        int tokl = w * 16 + (l >> 4) * 4 + rr;
        #pragma unroll
        for (int j = 0; j < 4; ++j) {
            int e = j * 16 + (l & 15);
            Oout[tokl * 64 + e] = f2bf(acc[j][rr] * (j < 2 ? zs : zo));
        }
    }
    __syncthreads();

    #pragma unroll
    for (int i = 0; i < 2; ++i) {
        int idx = i * 256 + t;
        int tokl = idx >> 3, ch = (idx & 7) * 8;
        short8 vv = *(short8*)&Oout[tokl * 64 + ch];
        *(short8*)&ATTbf[((size_t)(b * NTOK + tb * 64 + tokl)) * CDIM + head * 64 + ch] = vv;
    }
}

// ---------------- v 5x5 depthwise conv (bf16 V) + gate (bf16 ATT, bf16 G) --------------
__global__ __launch_bounds__(256) void voutg2_kernel(const ushort* __restrict__ Vbf,
                                                     const ushort* __restrict__ ATTbf,
                                                     const ushort* __restrict__ Gbf,
                                                     const float* __restrict__ dwc_w,
                                                     const float* __restrict__ dwc_b,
                                                     ushort* __restrict__ PRE) {
    const int t = threadIdx.x;
    const int c0 = t * 2;
    const int xpos = blockIdx.x;
    const int byc = blockIdx.y;
    const int b = byc >> 2, yc = byc & 3;
    const int y0 = yc * 14;
    const int dch = c0 & 63;

    float wgt[25][2];
    #pragma unroll
    for (int tap = 0; tap < 25; ++tap) {
        wgt[tap][0] = dwc_w[dch * 25 + tap];
        wgt[tap][1] = dwc_w[(dch + 1) * 25 + tap];
    }
    const float bias0 = dwc_b[dch], bias1 = dwc_b[dch + 1];
    const size_t base = (size_t)b * NTOK * CDIM + c0;

    float2 win[5][5];
    auto ldrow = [&](int yy, float2* dst) {
        #pragma unroll
        for (int dx = 0; dx < 5; ++dx) {
            int xx = xpos + dx - 2;
            bool ok = (yy >= 0 && yy < HW && xx >= 0 && xx < HW);
            if (ok) {
                ushort2 uv = *(const ushort2*)(Vbf + base + ((size_t)(yy * HW + xx) << 9));
                dst[dx] = make_float2(bf2f(uv.x), bf2f(uv.y));
            } else {
                dst[dx] = make_float2(0.f, 0.f);
            }
        }
    };
    ldrow(y0 - 2, win[0]);
    ldrow(y0 - 1, win[1]);
    ldrow(y0,     win[2]);
    ldrow(y0 + 1, win[3]);

    #pragma unroll
    for (int i = 0; i < 14; ++i) {
        int y = y0 + i;
        ldrow(y + 2, win[(i + 4) % 5]);
        float a0 = bias0, a1 = bias1;
        #pragma unroll
        for (int dy = 0; dy < 5; ++dy) {
            float2* row = win[(i + dy) % 5];
            #pragma unroll
            for (int dx = 0; dx < 5; ++dx) {
                a0 = fmaf(row[dx].x, wgt[dy * 5 + dx][0], a0);
                a1 = fmaf(row[dx].y, wgt[dy * 5 + dx][1], a1);
            }
        }
        size_t oidx = base + ((size_t)(y * HW + xpos) << 9);
        ushort2 au = *(const ushort2*)(ATTbf + oidx);
        ushort2 gu = *(const ushort2*)(Gbf + oidx);
        ushort2 o;
        o.x = f2bf((bf2f(au.x) + a0) * bf2f(gu.x));
        o.y = f2bf((bf2f(au.y) + a1) * bf2f(gu.y));
        *(ushort2*)(PRE + oidx) = o;
    }
}

extern "C" void kernel_launch(void* const* d_in, const int* in_sizes, int n_in,
                              void* d_out, int out_size, void* d_ws, size_t ws_size,
                              hipStream_t stream) {
    const float* x      = (const float*)d_in[0];
    const float* qg_w   = (const float*)d_in[1];
    const float* kv_w   = (const float*)d_in[2];
    const float* proj_w = (const float*)d_in[3];
    const float* proj_b = (const float*)d_in[4];
    const float* dwc_w  = (const float*)d_in[5];
    const float* dwc_b  = (const float*)d_in[6];
    const float* power_p= (const float*)d_in[7];
    const float* scale_p= (const float*)d_in[8];
    const float* enh_w  = (const float*)d_in[9];
    const float* bn_g   = (const float*)d_in[10];
    const float* bn_b   = (const float*)d_in[11];
    const float* ew_p   = (const float*)d_in[12];
    const float* pos    = (const float*)d_in[13];

    const size_t NELEM = (size_t)MTOT * CDIM;   // 12,845,056
    float* ws    = (float*)d_ws;
    ushort* Qbf  = (ushort*)ws;
    ushort* Gbf  = (ushort*)(ws + NELEM);
    float*  PKV_A= ws + NELEM + NELEM / 2;
    ushort* KFbf = (ushort*)(ws + 2 * NELEM);
    ushort* PREbf= (ushort*)(ws + 2 * NELEM);
    ushort* Vbf  = (ushort*)(ws + 3 * NELEM);
    ushort* ATTbf= (ushort*)(ws + 3 * NELEM + NELEM / 2);
    ushort* Xbf  = (ushort*)(ws + 4 * NELEM);
    ushort* QEbf = (ushort*)(ws + 4 * NELEM);
    float*  PKV_B= ws + 4 * NELEM + NELEM / 2;
    float* SMALL = ws + 5 * NELEM;
    float* ssum  = SMALL;               // 512
    float* ssq   = SMALL + 512;         // 512
    ushort* kvTbf= (ushort*)(SMALL + 9216);
    float* invs  = SMALL + 533504;
    float* powr  = SMALL + 534016;
    ushort* Wqg  = (ushort*)(SMALL + 535552);
    ushort* Wkv  = (ushort*)(SMALL + 797696);
    ushort* Wproj= (ushort*)(SMALL + 1059840);

    hipMemsetAsync(SMALL, 0, (size_t)1024 * sizeof(float), stream);

    cvt_all_kernel<<<13826, 256, 0, stream>>>(x, Xbf, qg_w, kv_w, proj_w,
                                              Wqg, Wkv, Wproj,
                                              scale_p, power_p, invs, powr);

    mgemm_qgkv<<<3136, 256, 0, stream>>>(Xbf, Wqg, Wkv, Qbf, Gbf, KFbf, Vbf, pos, invs, powr);

    fused_mid_kernel<<<2688, 256, 0, stream>>>(KFbf, Vbf, PKV_A, PKV_B,
                                               Qbf, enh_w, QEbf, ssum, ssq);

    kvreduce2_kernel<<<2560, 256, 0, stream>>>(PKV_A, PKV_B, kvTbf);

    attn_mfma_kernel<<<dim3(64, 49), 256, 0, stream>>>(Qbf, QEbf, kvTbf, powr,
                                                       ssum, ssq, bn_g, bn_b,
                                                       invs, ew_p, ATTbf);

    voutg2_kernel<<<dim3(56, 32), 256, 0, stream>>>(Vbf, ATTbf, Gbf, dwc_w, dwc_b, PREbf);

    mgemm_proj<<<784, 256, 0, stream>>>(PREbf, Wproj, (float*)d_out, proj_b);
}

// Round 21
// 447.737 us; speedup vs baseline: 1.2085x; 1.0036x over previous
//
#include <hip/hip_runtime.h>
#include <hip/hip_bf16.h>
#include <math.h>

#define CDIM 512
#define NTOK 3136
#define BATCH 8
#define MTOT (BATCH*NTOK)   // 25088
#define NHEAD 8
#define DHEAD 64
#define HW 56

typedef __attribute__((ext_vector_type(8))) short short8;
typedef __attribute__((ext_vector_type(4))) float f32x4;

__device__ __forceinline__ ushort f2bf(float f) {
    union { float f; unsigned int u; } v; v.f = f;
    unsigned int u = v.u + 0x7FFFu + ((v.u >> 16) & 1u);
    return (ushort)(u >> 16);
}
__device__ __forceinline__ float bf2f(ushort u) {
    union { unsigned int u; float f; } v; v.u = ((unsigned int)u) << 16;
    return v.f;
}

__device__ __forceinline__ void gload_lds16(const void* g, void* lds) {
    __builtin_amdgcn_global_load_lds((const __attribute__((address_space(1))) void*)g,
                                     (__attribute__((address_space(3))) void*)lds,
                                     16, 0, 0);
}

// ---------------- all input conversions + prep in ONE launch ----------------
// blocks [0,12544): x -> Xbf ; [12544,13824): weights ; 13824/13825: prep
__global__ __launch_bounds__(256) void cvt_all_kernel(const float* __restrict__ x,
                                                      ushort* __restrict__ Xbf,
                                                      const float* __restrict__ qg_w,
                                                      const float* __restrict__ kv_w,
                                                      const float* __restrict__ proj_w,
                                                      ushort* __restrict__ Wqg,
                                                      ushort* __restrict__ Wkv,
                                                      ushort* __restrict__ Wproj,
                                                      const float* __restrict__ scale_p,
                                                      const float* __restrict__ power_p,
                                                      float* __restrict__ inv_scale,
                                                      float* __restrict__ power) {
    int blk = blockIdx.x;
    if (blk < 12544) {
        int i = blk * 256 + threadIdx.x;
        float4 f = ((const float4*)x)[i];
        ushort4 o;
        o.x = f2bf(f.x); o.y = f2bf(f.y); o.z = f2bf(f.z); o.w = f2bf(f.w);
        ((ushort4*)Xbf)[i] = o;
        return;
    }
    if (blk >= 13824) {
        int c = (blk - 13824) * 256 + threadIdx.x;
        float s = log1pf(expf(scale_p[c]));
        inv_scale[c] = 1.0f / s;
        power[c] = 1.0f + 4.0f / (1.0f + expf(-power_p[c]));
        return;
    }
    int i = (blk - 12544) * 256 + threadIdx.x;
    const float* src; ushort* dst; int idx;
    if (i < 131072)      { src = qg_w;   dst = Wqg;   idx = i; }
    else if (i < 262144) { src = kv_w;   dst = Wkv;   idx = i - 131072; }
    else                 { src = proj_w; dst = Wproj; idx = i - 262144; }
    float4 f = ((const float4*)src)[idx];
    ushort4 o;
    o.x = f2bf(f.x); o.y = f2bf(f.y); o.z = f2bf(f.z); o.w = f2bf(f.w);
    ((ushort4*)dst)[idx] = o;
}

// ---------------- merged qg+kv GEMM: BK=32 x 3-buffer counted-vmcnt pipeline (48KB),
// 3 blocks/CU, 16B-store epilogue. grid 3136; idp=(bid&7)*392+(bid>>3); mb=idp>>4, ob=idp&15.
__global__ __launch_bounds__(256, 3) void mgemm_qgkv(const ushort* __restrict__ A,
                                                     const ushort* __restrict__ Wqg,
                                                     const ushort* __restrict__ Wkv,
                                                     ushort* __restrict__ Qout,
                                                     ushort* __restrict__ Gout,
                                                     ushort* __restrict__ KFout,
                                                     ushort* __restrict__ Vout,
                                                     const float* __restrict__ pos,
                                                     const float* __restrict__ invs,
                                                     const float* __restrict__ powr) {
    __shared__ __align__(16) char smem[49152];
    ushort* At = (ushort*)smem;               // [3][128*32]
    ushort* Bt = (ushort*)(smem + 24576);     // [3][128*32]
    float*  Osh = (float*)smem;               // epilogue alias [64][128]

    const int t = threadIdx.x;
    const int w = t >> 6, l = t & 63;
    const int wr = w >> 1, wc = w & 1;

    const int bid = blockIdx.x;
    const int idp = (bid & 7) * 392 + (bid >> 3);
    const int mb = idp >> 4, ob = idp & 15;
    const int m0 = mb * 128;
    const ushort* Bp = (ob < 8) ? (Wqg + (size_t)ob * 128 * CDIM)
                                : (Wkv + (size_t)(ob - 8) * 128 * CDIM);

    auto stage = [&](int buf, int ks) {
        const int k0 = ks * 32;
        #pragma unroll
        for (int i = 0; i < 2; ++i) {
            int f = t + i * 256;
            int row = f >> 2, ps = f & 3;
            int ls = ps ^ ((row >> 1) & 3);
            gload_lds16(A + (size_t)(m0 + row) * CDIM + k0 + ls * 8, At + buf * 4096 + f * 8);
            gload_lds16(Bp + (size_t)row * CDIM + k0 + ls * 8, Bt + buf * 4096 + f * 8);
        }
    };

    f32x4 acc[4][4] = {};
    stage(0, 0);
    stage(1, 1);
    const int sl4 = l >> 4;
    for (int ks = 0; ks < 16; ++ks) {
        if (ks < 15) asm volatile("s_waitcnt vmcnt(4)" ::: "memory");
        else         asm volatile("s_waitcnt vmcnt(0)" ::: "memory");
        __builtin_amdgcn_s_barrier();
        if (ks + 2 < 16) stage((ks + 2) % 3, ks + 2);
        const int cur = ks % 3;
        short8 af[4], bfr[4];
        #pragma unroll
        for (int i = 0; i < 4; ++i) {
            int row = wr * 64 + i * 16 + (l & 15);
            int ph = sl4 ^ ((row >> 1) & 3);
            af[i] = *(const short8*)&At[cur * 4096 + row * 32 + ph * 8];
            int rowb = wc * 64 + i * 16 + (l & 15);
            int phb = sl4 ^ ((rowb >> 1) & 3);
            bfr[i] = *(const short8*)&Bt[cur * 4096 + rowb * 32 + phb * 8];
        }
        #pragma unroll
        for (int i = 0; i < 4; ++i)
            #pragma unroll
            for (int j = 0; j < 4; ++j)
                acc[i][j] = __builtin_amdgcn_mfma_f32_16x16x32_bf16(af[i], bfr[j], acc[i][j], 0, 0, 0);
    }
    __syncthreads();

    const int colbase = ob * 128;
    #pragma unroll
    for (int p = 0; p < 2; ++p) {
        if (wr == p) {
            #pragma unroll
            for (int i = 0; i < 4; ++i)
                #pragma unroll
                for (int j = 0; j < 4; ++j)
                    #pragma unroll
                    for (int rr = 0; rr < 4; ++rr) {
                        int row = i * 16 + (l >> 4) * 4 + rr;
                        int col = wc * 64 + j * 16 + (l & 15);
                        int pc = col ^ (((row >> 2) & 1) << 4);
                        Osh[row * 128 + pc] = acc[i][j][rr];
                    }
        }
        __syncthreads();
        #pragma unroll
        for (int q = 0; q < 4; ++q) {
            int fi = q * 256 + t;
            int rl = fi >> 4;
            int c8 = (fi & 15) * 8;
            int xo = ((rl >> 2) & 1) << 4;
            float4 va = *(float4*)&Osh[rl * 128 + (c8 ^ xo)];
            float4 vb = *(float4*)&Osh[rl * 128 + ((c8 + 4) ^ xo)];
            int m = m0 + p * 64 + rl;
            if (colbase < 512) {
                union { ushort u[8]; short8 s; } o;
                o.u[0]=f2bf(va.x); o.u[1]=f2bf(va.y); o.u[2]=f2bf(va.z); o.u[3]=f2bf(va.w);
                o.u[4]=f2bf(vb.x); o.u[5]=f2bf(vb.y); o.u[6]=f2bf(vb.z); o.u[7]=f2bf(vb.w);
                *(short8*)&Qout[(size_t)m * CDIM + colbase + c8] = o.s;
            } else if (colbase < 1024) {
                union { ushort u[8]; short8 s; } o;
                o.u[0]=f2bf(va.x); o.u[1]=f2bf(va.y); o.u[2]=f2bf(va.z); o.u[3]=f2bf(va.w);
                o.u[4]=f2bf(vb.x); o.u[5]=f2bf(vb.y); o.u[6]=f2bf(vb.z); o.u[7]=f2bf(vb.w);
                *(short8*)&Gout[(size_t)m * CDIM + colbase - 512 + c8] = o.s;
            } else if (colbase < 1536) {
                int n = m % NTOK;
                int oc = colbase - 1024 + c8;
                const float* pp = &pos[(size_t)n * CDIM + oc];
                float4 pva = *(const float4*)pp;
                float4 pvb = *(const float4*)(pp + 4);
                float4 iva = *(const float4*)&invs[oc];
                float4 ivb = *(const float4*)&invs[oc + 4];
                float4 pwa = *(const float4*)&powr[oc];
                float4 pwb = *(const float4*)&powr[oc + 4];
                float kx[8], tp[8];
                kx[0]=(va.x+pva.x)*iva.x; kx[1]=(va.y+pva.y)*iva.y;
                kx[2]=(va.z+pva.z)*iva.z; kx[3]=(va.w+pva.w)*iva.w;
                kx[4]=(vb.x+pvb.x)*ivb.x; kx[5]=(vb.y+pvb.y)*ivb.y;
                kx[6]=(vb.z+pvb.z)*ivb.z; kx[7]=(vb.w+pvb.w)*ivb.w;
                tp[0]=__powf(fabsf(kx[0]),pwa.x); tp[1]=__powf(fabsf(kx[1]),pwa.y);
                tp[2]=__powf(fabsf(kx[2]),pwa.z); tp[3]=__powf(fabsf(kx[3]),pwa.w);
                tp[4]=__powf(fabsf(kx[4]),pwb.x); tp[5]=__powf(fabsf(kx[5]),pwb.y);
                tp[6]=__powf(fabsf(kx[6]),pwb.z); tp[7]=__powf(fabsf(kx[7]),pwb.w);
                union { ushort u[8]; short8 s; } up, un;
                #pragma unroll
                for (int e = 0; e < 8; ++e) {
                    ushort bb = f2bf(tp[e]);
                    up.u[e] = kx[e] > 0.f ? bb : (ushort)0;
                    un.u[e] = kx[e] < 0.f ? bb : (ushort)0;
                }
                ushort* dst = KFout + (size_t)m * 1024 + ((oc >> 6) << 7) + (oc & 63);
                *(short8*)dst = up.s;
                *(short8*)(dst + 64) = un.s;
            } else {
                union { ushort u[8]; short8 s; } o;
                o.u[0]=f2bf(va.x); o.u[1]=f2bf(va.y); o.u[2]=f2bf(va.z); o.u[3]=f2bf(va.w);
                o.u[4]=f2bf(vb.x); o.u[5]=f2bf(vb.y); o.u[6]=f2bf(vb.z); o.u[7]=f2bf(vb.w);
                *(short8*)&Vout[(size_t)m * CDIM + colbase - 1536 + c8] = o.s;
            }
        }
        __syncthreads();
    }
}

// ---------------- proj GEMM: BK=32 x 3-buffer counted-vmcnt pipeline, XOR fp32 epilogue --
__global__ __launch_bounds__(256, 3) void mgemm_proj(const ushort* __restrict__ A,
                                                     const ushort* __restrict__ W,
                                                     float* __restrict__ out,
                                                     const float* __restrict__ pb) {
    __shared__ __align__(16) char smem[49152];
    ushort* At = (ushort*)smem;
    ushort* Bt = (ushort*)(smem + 24576);
    float*  Osh = (float*)smem;               // [64][128] alias

    const int t = threadIdx.x;
    const int w = t >> 6, l = t & 63;
    const int wr = w >> 1, wc = w & 1;

    const int bid = blockIdx.x;
    const int idp = (bid & 7) * 98 + (bid >> 3);
    const int mb = idp >> 2, ob = idp & 3;
    const int m0 = mb * 128;
    const ushort* Bp = W + (size_t)ob * 128 * CDIM;

    auto stage = [&](int buf, int ks) {
        const int k0 = ks * 32;
        #pragma unroll
        for (int i = 0; i < 2; ++i) {
            int f = t + i * 256;
            int row = f >> 2, ps = f & 3;
            int ls = ps ^ ((row >> 1) & 3);
            gload_lds16(A + (size_t)(m0 + row) * CDIM + k0 + ls * 8, At + buf * 4096 + f * 8);
            gload_lds16(Bp + (size_t)row * CDIM + k0 + ls * 8, Bt + buf * 4096 + f * 8);
        }
    };

    f32x4 acc[4][4] = {};
    stage(0, 0);
    stage(1, 1);
    const int sl4 = l >> 4;
    for (int ks = 0; ks < 16; ++ks) {
        if (ks < 15) asm volatile("s_waitcnt vmcnt(4)" ::: "memory");
        else         asm volatile("s_waitcnt vmcnt(0)" ::: "memory");
        __builtin_amdgcn_s_barrier();
        if (ks + 2 < 16) stage((ks + 2) % 3, ks + 2);
        const int cur = ks % 3;
        short8 af[4], bfr[4];
        #pragma unroll
        for (int i = 0; i < 4; ++i) {
            int row = wr * 64 + i * 16 + (l & 15);
            int ph = sl4 ^ ((row >> 1) & 3);
            af[i] = *(const short8*)&At[cur * 4096 + row * 32 + ph * 8];
            int rowb = wc * 64 + i * 16 + (l & 15);
            int phb = sl4 ^ ((rowb >> 1) & 3);
            bfr[i] = *(const short8*)&Bt[cur * 4096 + rowb * 32 + phb * 8];
        }
        #pragma unroll
        for (int i = 0; i < 4; ++i)
            #pragma unroll
            for (int j = 0; j < 4; ++j)
                acc[i][j] = __builtin_amdgcn_mfma_f32_16x16x32_bf16(af[i], bfr[j], acc[i][j], 0, 0, 0);
    }
    __syncthreads();

    const int colbase = ob * 128;
    #pragma unroll
    for (int p = 0; p < 2; ++p) {
        if (wr == p) {
            #pragma unroll
            for (int i = 0; i < 4; ++i)
                #pragma unroll
                for (int j = 0; j < 4; ++j)
                    #pragma unroll
                    for (int rr = 0; rr < 4; ++rr) {
                        int row = i * 16 + (l >> 4) * 4 + rr;
                        int col = wc * 64 + j * 16 + (l & 15);
                        int pc = col ^ (((row >> 2) & 1) << 4);
                        Osh[row * 128 + pc] = acc[i][j][rr];
                    }
        }
        __syncthreads();
        #pragma unroll
        for (int q = 0; q < 8; ++q) {
            int fi = q * 256 + t;
            int rl = fi >> 5, c4 = (fi & 31) * 4;
            int pc4 = c4 ^ (((rl >> 2) & 1) << 4);
            float4 v = *(float4*)&Osh[rl * 128 + pc4];
            float4 b4 = *(const float4*)&pb[colbase + c4];
            v.x += b4.x; v.y += b4.y; v.z += b4.z; v.w += b4.w;
            *(float4*)&out[(size_t)(m0 + p * 64 + rl) * CDIM + colbase + c4] = v;
        }
        __syncthreads();
    }
}

// ---------------- FUSED mid: kvred4 (blocks 0..895) || conv3s (blocks 896..2687) -------
__global__ __launch_bounds__(256) void fused_mid_kernel(const ushort* __restrict__ KF,
                                                        const ushort* __restrict__ Vbf,
                                                        float* __restrict__ PKV_A,
                                                        float* __restrict__ PKV_B,
                                                        const ushort* __restrict__ Qbf,
                                                        const float* __restrict__ enh_w,
                                                        ushort* __restrict__ QEbf,
                                                        float* __restrict__ ssum,
                                                        float* __restrict__ ssq) {
    const int blk = blockIdx.x;
    const int t = threadIdx.x;
    if (blk < 896) {
        // ---- kvred4 ----
        const int bh = blk & 63, chunk = blk >> 6;      // 0..13
        const int b = bh >> 3, head = bh & 7;
        const int w = t >> 6, l = t & 63;
        const int lr = l & 15;
        const int ns = (l >> 4) * 8;

        const int nbase = b * NTOK + chunk * 224;
        const ushort* kf0 = KF  + ((size_t)(nbase + ns)) * 1024 + head * 128 + (w * 32 + lr);
        const ushort* vb0 = Vbf + ((size_t)(nbase + ns)) * 512  + head * 64  + lr;

        short8 ones;
        #pragma unroll
        for (int j = 0; j < 8; ++j) ones[j] = (lr == 0) ? (short)0x3F80 : (short)0;

        f32x4 acc[2][5] = {};
        for (int tile = 0; tile < 7; ++tile) {
            union { uint u[4]; short8 s; } ua[2], ub[4];
            #pragma unroll
            for (int i = 0; i < 2; ++i) {
                #pragma unroll
                for (int j = 0; j < 4; ++j) {
                    uint lo = kf0[i * 16 + (size_t)(2 * j) * 1024];
                    uint hi = kf0[i * 16 + (size_t)(2 * j + 1) * 1024];
                    ua[i].u[j] = lo | (hi << 16);
                }
            }
            #pragma unroll
            for (int j5 = 0; j5 < 4; ++j5) {
                #pragma unroll
                for (int j = 0; j < 4; ++j) {
                    uint lo = vb0[j5 * 16 + (size_t)(2 * j) * 512];
                    uint hi = vb0[j5 * 16 + (size_t)(2 * j + 1) * 512];
                    ub[j5].u[j] = lo | (hi << 16);
                }
            }
            #pragma unroll
            for (int i = 0; i < 2; ++i) {
                #pragma unroll
                for (int j5 = 0; j5 < 4; ++j5)
                    acc[i][j5] = __builtin_amdgcn_mfma_f32_16x16x32_bf16(ua[i].s, ub[j5].s, acc[i][j5], 0, 0, 0);
                acc[i][4] = __builtin_amdgcn_mfma_f32_16x16x32_bf16(ua[i].s, ones, acc[i][4], 0, 0, 0);
            }
            kf0 += (size_t)32 * 1024;
            vb0 += (size_t)32 * 512;
        }
        float* dstb = (chunk < 7)
            ? (PKV_A + ((size_t)(chunk * 64 + bh)) * 8320)
            : (PKV_B + ((size_t)((chunk - 7) * 64 + bh)) * 8320);
        #pragma unroll
        for (int i = 0; i < 2; ++i) {
            int d0 = w * 32 + i * 16 + (l >> 4) * 4;
            #pragma unroll
            for (int j = 0; j < 5; ++j) {
                int e = j * 16 + lr;
                if (j < 4 || e == 64)
                    *(f32x4*)(dstb + (size_t)e * 128 + d0) = acc[i][j];
            }
        }
        return;
    }
    // ---- conv3s ----
    {
        const int idx = blk - 896;
        const int xpos = idx % 56;
        const int byc = idx / 56;
        const int c0 = t * 2;
        const int b = byc >> 2, yc = byc & 3;
        const int y0 = yc * 14;

        float wgt[9][2];
        #pragma unroll
        for (int tap = 0; tap < 9; ++tap) {
            wgt[tap][0] = enh_w[c0 * 9 + tap];
            wgt[tap][1] = enh_w[(c0 + 1) * 9 + tap];
        }
        const size_t base = (size_t)b * NTOK * CDIM + c0;

        float2 win[3][3];
        auto ldrow = [&](int yy, float2* dst) {
            #pragma unroll
            for (int dx = 0; dx < 3; ++dx) {
                int xx = xpos + dx - 1;
                bool ok = (yy >= 0 && yy < HW && xx >= 0 && xx < HW);
                if (ok) {
                    ushort2 uv = *(const ushort2*)(Qbf + base + ((size_t)(yy * HW + xx) << 9));
                    dst[dx] = make_float2(bf2f(uv.x), bf2f(uv.y));
                } else {
                    dst[dx] = make_float2(0.f, 0.f);
                }
            }
        };
        ldrow(y0 - 1, win[0]);
        ldrow(y0,     win[1]);

        float s1a = 0.f, s2a = 0.f, s1b = 0.f, s2b = 0.f;
        #pragma unroll
        for (int i = 0; i < 14; ++i) {
            int y = y0 + i;
            ldrow(y + 1, win[(i + 2) % 3]);
            float a0 = 0.f, a1 = 0.f;
            #pragma unroll
            for (int dy = 0; dy < 3; ++dy) {
                float2* row = win[(i + dy) % 3];
                #pragma unroll
                for (int dx = 0; dx < 3; ++dx) {
                    a0 = fmaf(row[dx].x, wgt[dy * 3 + dx][0], a0);
                    a1 = fmaf(row[dx].y, wgt[dy * 3 + dx][1], a1);
                }
            }
            ushort2 o; o.x = f2bf(a0); o.y = f2bf(a1);
            *(ushort2*)(QEbf + base + ((size_t)(y * HW + xpos) << 9)) = o;
            s1a += a0; s2a += a0 * a0;
            s1b += a1; s2b += a1 * a1;
        }
        atomicAdd(&ssum[c0], s1a);     atomicAdd(&ssq[c0], s2a);
        atomicAdd(&ssum[c0 + 1], s1b); atomicAdd(&ssq[c0 + 1], s2b);
    }
}

// ---------------- reduce split partials -> pre-swizzled bf16 BT image [bh][80][128] -----
__global__ __launch_bounds__(256) void kvreduce2_kernel(const float* __restrict__ PKV_A,
                                                        const float* __restrict__ PKV_B,
                                                        ushort* __restrict__ kvTbf) {
    int gid = blockIdx.x * 256 + threadIdx.x;
    const float inv_n = 1.0f / (float)NTOK;
    int bh = gid / 10240;
    int r  = gid - bh * 10240;
    int row = r >> 7, dcol = r & 127;
    int dlog = (((dcol >> 3) ^ (row & 7)) << 3) | (dcol & 7);
    float s = 0.f;
    if (row < 66) {
        int rsel, dsel;
        if (row < 64) { rsel = row; dsel = (row >= 32) ? (dlog ^ 64) : dlog; }
        else          { rsel = 64;  dsel = (row == 65) ? (dlog ^ 64) : dlog; }
        size_t idx = (size_t)bh * 8320 + rsel * 128 + dsel;
        #pragma unroll
        for (int c = 0; c < 7; ++c) s += PKV_A[(size_t)c * 532480 + idx];
        #pragma unroll
        for (int c = 0; c < 7; ++c) s += PKV_B[(size_t)c * 532480 + idx];
    }
    kvTbf[gid] = (row < 66) ? f2bf(s * inv_n) : (ushort)0;
}

// ---------------- attention apply via MFMA (qfin + BN-prep fused) -------------------
__global__ __launch_bounds__(256) void attn_mfma_kernel(const ushort* __restrict__ Qbf,
                                                        const ushort* __restrict__ QEbf,
                                                        const ushort* __restrict__ kvTbf,
                                                        const float* __restrict__ power,
                                                        const float* __restrict__ ssum,
                                                        const float* __restrict__ ssq,
                                                        const float* __restrict__ bn_g,
                                                        const float* __restrict__ bn_b,
                                                        const float* __restrict__ invs,
                                                        const float* __restrict__ ewp,
                                                        ushort* __restrict__ ATTbf) {
    __shared__ ushort QF[64 * 128];
    __shared__ ushort BT[80 * 128];
    const int bh = blockIdx.x, tb = blockIdx.y;
    const int b = bh >> 3, head = bh & 7;
    const int t = threadIdx.x;
    const int w = t >> 6, l = t & 63;

    #pragma unroll
    for (int i = 0; i < 5; ++i) {
        int f = i * 256 + t;
        gload_lds16(kvTbf + (size_t)bh * 10240 + f * 8, BT + f * 8);
    }

    const int c = l, hc = head * 64 + c;
    const float p = power[hc];
    const float invM = 1.0f / (float)MTOT;
    float mean = ssum[hc] * invM;
    float var  = ssq[hc] * invM - mean * mean;
    const float ac = bn_g[hc] * rsqrtf(var + 1e-5f);
    const float bc = bn_b[hc] - mean * ac;
    const float iv = invs[hc], ew = ewp[0];
    #pragma unroll
    for (int i = 0; i < 16; ++i) {
        int tok = i * 4 + w;
        size_t off = ((size_t)(b * NTOK + tb * 64 + tok)) * CDIM + hc;
        float q = bf2f(Qbf[off]);
        float qe = bf2f(QEbf[off]);
        q = (q + ew * fmaxf(fmaf(ac, qe, bc), 0.f)) * iv;
        float ax = fabsf(q);
        float tp = ax > 0.f ? __powf(ax, p) : 0.f;
        float qp = q > 0.f ? tp : 0.f;
        float qn = q < 0.f ? tp : 0.f;
        int sw = tok & 7;
        QF[tok * 128 + (((c >> 3) ^ sw) * 8) + (c & 7)]       = f2bf(qp);
        QF[tok * 128 + ((((c >> 3) + 8) ^ sw) * 8) + (c & 7)] = f2bf(qn);
    }
    __syncthreads();

    f32x4 acc[5] = {};
    #pragma unroll
    for (int kk = 0; kk < 4; ++kk) {
        int sbase = kk * 4 + (l >> 4);
        int rowa = w * 16 + (l & 15);
        short8 af = *(const short8*)&QF[rowa * 128 + ((sbase ^ (rowa & 7)) * 8)];
        #pragma unroll
        for (int j = 0; j < 5; ++j) {
            int rowb = j * 16 + (l & 15);
            short8 bf = *(const short8*)&BT[rowb * 128 + ((sbase ^ (rowb & 7)) * 8)];
            acc[j] = __builtin_amdgcn_mfma_f32_16x16x32_bf16(af, bf, acc[j], 0, 0, 0);
        }
    }
    __syncthreads();

    ushort* Oout = QF;
    #pragma unroll
    for (int rr = 0; rr < 4; ++rr) {
        float ssim = __shfl(acc[4][rr], (l & 48));
        float sopp = __shfl(acc[4][rr], (l & 48) + 1);
        float zs = 1.f / (ssim + 1e-6f);
        float zo = 1.f / (sopp + 1e-6f);
        int tokl = w * 16 + (l >> 4) * 4 + rr;
        #pragma unroll
        for (int j = 0; j < 4; ++j) {
            int e = j * 16 + (l & 15);
            Oout[tokl * 64 + e] = f2bf(acc[j][rr] * (j < 2 ? zs : zo));
        }
    }
    __syncthreads();

    #pragma unroll
    for (int i = 0; i < 2; ++i) {
        int idx = i * 256 + t;
        int tokl = idx >> 3, ch = (idx & 7) * 8;
        short8 vv = *(short8*)&Oout[tokl * 64 + ch];
        *(short8*)&ATTbf[((size_t)(b * NTOK + tb * 64 + tokl)) * CDIM + head * 64 + ch] = vv;
    }
}

// ---------------- v 5x5 depthwise conv (bf16 V) + gate (bf16 ATT, bf16 G) --------------
__global__ __launch_bounds__(256) void voutg2_kernel(const ushort* __restrict__ Vbf,
                                                     const ushort* __restrict__ ATTbf,
                                                     const ushort* __restrict__ Gbf,
                                                     const float* __restrict__ dwc_w,
                                                     const float* __restrict__ dwc_b,
                                                     ushort* __restrict__ PRE) {
    const int t = threadIdx.x;
    const int c0 = t * 2;
    const int xpos = blockIdx.x;
    const int byc = blockIdx.y;
    const int b = byc >> 2, yc = byc & 3;
    const int y0 = yc * 14;
    const int dch = c0 & 63;

    float wgt[25][2];
    #pragma unroll
    for (int tap = 0; tap < 25; ++tap) {
        wgt[tap][0] = dwc_w[dch * 25 + tap];
        wgt[tap][1] = dwc_w[(dch + 1) * 25 + tap];
    }
    const float bias0 = dwc_b[dch], bias1 = dwc_b[dch + 1];
    const size_t base = (size_t)b * NTOK * CDIM + c0;

    float2 win[5][5];
    auto ldrow = [&](int yy, float2* dst) {
        #pragma unroll
        for (int dx = 0; dx < 5; ++dx) {
            int xx = xpos + dx - 2;
            bool ok = (yy >= 0 && yy < HW && xx >= 0 && xx < HW);
            if (ok) {
                ushort2 uv = *(const ushort2*)(Vbf + base + ((size_t)(yy * HW + xx) << 9));
                dst[dx] = make_float2(bf2f(uv.x), bf2f(uv.y));
            } else {
                dst[dx] = make_float2(0.f, 0.f);
            }
        }
    };
    ldrow(y0 - 2, win[0]);
    ldrow(y0 - 1, win[1]);
    ldrow(y0,     win[2]);
    ldrow(y0 + 1, win[3]);

    #pragma unroll
    for (int i = 0; i < 14; ++i) {
        int y = y0 + i;
        ldrow(y + 2, win[(i + 4) % 5]);
        float a0 = bias0, a1 = bias1;
        #pragma unroll
        for (int dy = 0; dy < 5; ++dy) {
            float2* row = win[(i + dy) % 5];
            #pragma unroll
            for (int dx = 0; dx < 5; ++dx) {
                a0 = fmaf(row[dx].x, wgt[dy * 5 + dx][0], a0);
                a1 = fmaf(row[dx].y, wgt[dy * 5 + dx][1], a1);
            }
        }
        size_t oidx = base + ((size_t)(y * HW + xpos) << 9);
        ushort2 au = *(const ushort2*)(ATTbf + oidx);
        ushort2 gu = *(const ushort2*)(Gbf + oidx);
        ushort2 o;
        o.x = f2bf((bf2f(au.x) + a0) * bf2f(gu.x));
        o.y = f2bf((bf2f(au.y) + a1) * bf2f(gu.y));
        *(ushort2*)(PRE + oidx) = o;
    }
}

extern "C" void kernel_launch(void* const* d_in, const int* in_sizes, int n_in,
                              void* d_out, int out_size, void* d_ws, size_t ws_size,
                              hipStream_t stream) {
    const float* x      = (const float*)d_in[0];
    const float* qg_w   = (const float*)d_in[1];
    const float* kv_w   = (const float*)d_in[2];
    const float* proj_w = (const float*)d_in[3];
    const float* proj_b = (const float*)d_in[4];
    const float* dwc_w  = (const float*)d_in[5];
    const float* dwc_b  = (const float*)d_in[6];
    const float* power_p= (const float*)d_in[7];
    const float* scale_p= (const float*)d_in[8];
    const float* enh_w  = (const float*)d_in[9];
    const float* bn_g   = (const float*)d_in[10];
    const float* bn_b   = (const float*)d_in[11];
    const float* ew_p   = (const float*)d_in[12];
    const float* pos    = (const float*)d_in[13];

    const size_t NELEM = (size_t)MTOT * CDIM;   // 12,845,056
    float* ws    = (float*)d_ws;
    ushort* Qbf  = (ushort*)ws;
    ushort* Gbf  = (ushort*)(ws + NELEM);
    float*  PKV_A= ws + NELEM + NELEM / 2;
    ushort* KFbf = (ushort*)(ws + 2 * NELEM);
    ushort* PREbf= (ushort*)(ws + 2 * NELEM);
    ushort* Vbf  = (ushort*)(ws + 3 * NELEM);
    ushort* ATTbf= (ushort*)(ws + 3 * NELEM + NELEM / 2);
    ushort* Xbf  = (ushort*)(ws + 4 * NELEM);
    ushort* QEbf = (ushort*)(ws + 4 * NELEM);
    float*  PKV_B= ws + 4 * NELEM + NELEM / 2;
    float* SMALL = ws + 5 * NELEM;
    float* ssum  = SMALL;               // 512
    float* ssq   = SMALL + 512;         // 512
    ushort* kvTbf= (ushort*)(SMALL + 9216);
    float* invs  = SMALL + 533504;
    float* powr  = SMALL + 534016;
    ushort* Wqg  = (ushort*)(SMALL + 535552);
    ushort* Wkv  = (ushort*)(SMALL + 797696);
    ushort* Wproj= (ushort*)(SMALL + 1059840);

    hipMemsetAsync(SMALL, 0, (size_t)1024 * sizeof(float), stream);

    cvt_all_kernel<<<13826, 256, 0, stream>>>(x, Xbf, qg_w, kv_w, proj_w,
                                              Wqg, Wkv, Wproj,
                                              scale_p, power_p, invs, powr);

    mgemm_qgkv<<<3136, 256, 0, stream>>>(Xbf, Wqg, Wkv, Qbf, Gbf, KFbf, Vbf, pos, invs, powr);

    fused_mid_kernel<<<2688, 256, 0, stream>>>(KFbf, Vbf, PKV_A, PKV_B,
                                               Qbf, enh_w, QEbf, ssum, ssq);

    kvreduce2_kernel<<<2560, 256, 0, stream>>>(PKV_A, PKV_B, kvTbf);

    attn_mfma_kernel<<<dim3(64, 49), 256, 0, stream>>>(Qbf, QEbf, kvTbf, powr,
                                                       ssum, ssq, bn_g, bn_b,
                                                       invs, ew_p, ATTbf);

    voutg2_kernel<<<dim3(56, 32), 256, 0, stream>>>(Vbf, ATTbf, Gbf, dwc_w, dwc_b, PREbf);

    mgemm_proj<<<784, 256, 0, stream>>>(PREbf, Wproj, (float*)d_out, proj_b);
}